// Round 7
// baseline (1591.849 us; speedup 1.0000x reference)
//
#include <hip/hip_runtime.h>
#include <stdint.h>
#include <math.h>

typedef short bf16x8 __attribute__((ext_vector_type(8)));
typedef float f32x4 __attribute__((ext_vector_type(4)));

#if __has_builtin(__builtin_amdgcn_exp2f)
#define EXP2F(x) __builtin_amdgcn_exp2f(x)
#else
#define EXP2F(x) exp2f(x)
#endif

static constexpr int Bn   = 2;
static constexpr int Sn   = 2048;
static constexpr int NH   = 32;
static constexpr int NKV  = 8;
static constexpr int Dh   = 128;
static constexpr int En   = NH * Dh;     // 4096
static constexpr int KVEn = NKV * Dh;    // 1024
static constexpr int QKVE = En + 2 * KVEn; // 6144 fused projection width
static constexpr int MT   = Bn * Sn;     // 4096 tokens
static constexpr int QT   = Sn / 128;    // 16 q-tiles (128 rows each)

__device__ __forceinline__ unsigned short f2bf(float f) {
  unsigned int u = __float_as_uint(f);
  u += 0x7FFFu + ((u >> 16) & 1u);
  return (unsigned short)(u >> 16);
}
__device__ __forceinline__ float bf2f(unsigned short h) {
  return __uint_as_float(((unsigned int)h) << 16);
}

typedef __attribute__((address_space(1))) void* gas_t;
typedef __attribute__((address_space(3))) void* las_t;
// async global->LDS, 16B per lane; lds dest must be wave-base + lane*16 (linear)
__device__ __forceinline__ void gl_lds16(const void* g, void* l) {
  __builtin_amdgcn_global_load_lds((gas_t)(uintptr_t)g, (las_t)(uint32_t)(uintptr_t)l,
                                   16, 0, 0);
}

#define VMW(n)  asm volatile("s_waitcnt vmcnt(" #n ")" ::: "memory")
#define LGKM0   asm volatile("s_waitcnt lgkmcnt(0)" ::: "memory")
#define SCHEDB  __builtin_amdgcn_sched_barrier(0)
#define BAR     __builtin_amdgcn_s_barrier()

// ---------------- pre/post passes ----------------

__global__ void cast_bf16_kernel(const float* __restrict__ x,
                                 unsigned short* __restrict__ y, int n4) {
  int i = blockIdx.x * 256 + threadIdx.x;
  if (i >= n4) return;
  float4 v = ((const float4*)x)[i];
  ushort4 o;
  o.x = f2bf(v.x); o.y = f2bf(v.y); o.z = f2bf(v.z); o.w = f2bf(v.w);
  ((ushort4*)y)[i] = o;
}

// W [R][C] f32 -> WT [C][R] bf16 (tiled, coalesced both sides)
__global__ void tcast_kernel(const float* __restrict__ W,
                             unsigned short* __restrict__ WT, int R, int C) {
  __shared__ float t[32][33];
  int tx = threadIdx.x, ty = threadIdx.y;
  int c = blockIdx.x * 32 + tx, r = blockIdx.y * 32 + ty;
  t[ty][tx] = W[(size_t)r * C + c];
  __syncthreads();
  int ro = blockIdx.x * 32 + ty, co = blockIdx.y * 32 + tx;
  WT[(size_t)ro * R + co] = f2bf(t[tx][ty]);
}

__global__ void rope_table_kernel(float2* __restrict__ cs) {
  int i = blockIdx.x * 256 + threadIdx.x;   // i < Sn*64
  int s = i >> 6, d = i & 63;
  float inv = powf(10000.0f, -(float)d * (1.0f / 64.0f));
  float a = (float)s * inv;
  cs[i] = make_float2(cosf(a), sinf(a));
}

// in-place RoPE on [MT][rowstride] starting at column 0 of q; pairs (d, d+64)
__global__ void rope_kernel(unsigned short* __restrict__ q,
                            const float2* __restrict__ cs, int rowstride, float scl) {
  int row = blockIdx.x;
  int s = row & (Sn - 1);
  int hl = threadIdx.x >> 6, d = threadIdx.x & 63;
  int h = blockIdx.y * 4 + hl;
  size_t base = (size_t)row * rowstride + (size_t)h * Dh + d;
  float2 c = cs[s * 64 + d];
  float x0 = bf2f(q[base]), x1 = bf2f(q[base + 64]);
  q[base]      = f2bf((x0 * c.x - x1 * c.y) * scl);
  q[base + 64] = f2bf((x1 * c.x + x0 * c.y) * scl);
}

// V (strided rows) -> Vt [B][KV][D][S]  (d-major so PV B-frags are k-contiguous)
__global__ void vtrans_kernel(const unsigned short* __restrict__ V, int rowstride,
                              unsigned short* __restrict__ Vt) {
  __shared__ unsigned short t[32][33];
  int bk = blockIdx.z;                 // b*NKV+kv
  int b = bk >> 3, kv = bk & 7;
  int d = blockIdx.x * 32 + threadIdx.x;
  int s = blockIdx.y * 32 + threadIdx.y;
  t[threadIdx.y][threadIdx.x] = V[(size_t)(b * Sn + s) * rowstride + kv * Dh + d];
  __syncthreads();
  int dd = blockIdx.x * 32 + threadIdx.y;
  int so = blockIdx.y * 32 + threadIdx.x;
  Vt[((size_t)bk * Dh + dd) * Sn + so] = t[threadIdx.x][threadIdx.y];
}

// ---------------- GEMM 256x256, m201-exact 8-phase ----------------
// A[M,K] bf16, BT[N,K] bf16 -> C[M,N]. 512 thr = 8 waves (2M x 4N), each wave
// owns a FIXED 128x64 output region. BK=64, 2 K-tiles per 8-phase iter.
// Register pipeline: 4 fragment banks (a0,a1 = M-quadrants; bb0,bb1 = B per
// K-tile); each phase issues <=8 ds_read_b128 feeding phase p+1, then 16 MFMA
// on regs awaited last phase, then lgkmcnt(0) (reads overlap MFMA).
// Stage schedule loads/phase = 2,2,4,0 cyclic -> any 4-phase window = 8
// -> uniform vmcnt(8): after phase p's barrier, all stages <= p-4 landed.
// All read-landing slacks and slot-overwrite orders verified phase-by-phase.
// One barrier per phase. Rows XOR-swizzled ((row&7)<<4), same involution on
// global source and ds_read. KT even, >= 4.

__global__ __launch_bounds__(512, 2) void gemm256_kernel(
    const unsigned short* __restrict__ A, const unsigned short* __restrict__ BT,
    void* __restrict__ Cout, int M, int N, int K, int out_f32) {
  __shared__ unsigned short lds[2][4][128 * 64];  // [buf][A0,A1,B0,B1]
  const int tid = threadIdx.x;
  const int lane = tid & 63, wave = tid >> 6;
  const int r15 = lane & 15, kg = lane >> 4;
  const int wm = wave >> 2, wn = wave & 3;        // wave region: 128M x 64N
  const int brow0 = (wn & 1) * 64;
  const int m0 = blockIdx.y * 256, n0 = blockIdx.x * 256;
  const char* Ab = (const char*)A;
  const char* Bb = (const char*)BT;
  const int KT = K >> 6;

  f32x4 acc[8][4] = {};           // [mf][nf] over wave's 128x64
  bf16x8 a0[4][2], a1[4][2];      // A frag banks: M-quadrant x ks
  bf16x8 bb0[4][2], bb1[4][2];    // B frag banks: per K-tile (even/odd)

#define STG(SRC, ROW0, TILE, SLOT)                                            \
  do {                                                                        \
    _Pragma("unroll") for (int ld = 0; ld < 2; ++ld) {                        \
      int _f = (ld * 512 + tid) * 16;                                         \
      int _row = _f >> 7, _cb = _f & 127;                                     \
      gl_lds16(SRC + ((size_t)((ROW0) + _row) * K + (size_t)(TILE) * 64) * 2 +\
                   (_cb ^ ((_row & 7) << 4)),                                 \
               (char*)(SLOT) + _f);                                           \
    }                                                                         \
  } while (0)

#define RD_A(DST, BUF, MQ)                                                    \
  do {                                                                        \
    const char* _b = (const char*)lds[BUF][wm];                               \
    _Pragma("unroll") for (int j = 0; j < 4; ++j) {                           \
      int _r = (MQ) * 64 + j * 16 + r15;                                      \
      int _s = (_r & 7) << 4;                                                 \
      DST[j][0] = *(const bf16x8*)(_b + _r * 128 + ((kg * 16) ^ _s));         \
      DST[j][1] = *(const bf16x8*)(_b + _r * 128 + ((64 + kg * 16) ^ _s));    \
    }                                                                         \
  } while (0)

#define RD_B(DST, BUF)                                                        \
  do {                                                                        \
    const char* _b = (const char*)lds[BUF][2 + (wn >> 1)];                    \
    _Pragma("unroll") for (int f = 0; f < 4; ++f) {                           \
      int _r = brow0 + f * 16 + r15;                                          \
      int _s = (_r & 7) << 4;                                                 \
      DST[f][0] = *(const bf16x8*)(_b + _r * 128 + ((kg * 16) ^ _s));         \
      DST[f][1] = *(const bf16x8*)(_b + _r * 128 + ((64 + kg * 16) ^ _s));    \
    }                                                                         \
  } while (0)

#define PH(MQ, NQ, AB, BB, RD, ST, WT, DOBAR)                                 \
  do {                                                                        \
    RD;                                                                       \
    ST;                                                                       \
    __builtin_amdgcn_s_setprio(1);                                            \
    _Pragma("unroll") for (int j = 0; j < 4; ++j)                             \
      _Pragma("unroll") for (int n2 = 0; n2 < 2; ++n2) {                      \
        acc[(MQ)*4 + j][(NQ)*2 + n2] =                                        \
            __builtin_amdgcn_mfma_f32_16x16x32_bf16(                          \
                AB[j][0], BB[(NQ)*2 + n2][0], acc[(MQ)*4 + j][(NQ)*2 + n2],   \
                0, 0, 0);                                                     \
        acc[(MQ)*4 + j][(NQ)*2 + n2] =                                        \
            __builtin_amdgcn_mfma_f32_16x16x32_bf16(                          \
                AB[j][1], BB[(NQ)*2 + n2][1], acc[(MQ)*4 + j][(NQ)*2 + n2],   \
                0, 0, 0);                                                     \
      }                                                                       \
    __builtin_amdgcn_s_setprio(0);                                            \
    LGKM0;                                                                    \
    SCHEDB;                                                                   \
    WT;                                                                       \
    if (DOBAR) { BAR; SCHEDB; }                                               \
  } while (0)

  // prologue: stage tiles 0,1 fully; drain once; preload bb0 + a0 of tile 0
  STG(Bb, n0,       0, lds[0][2]); STG(Bb, n0 + 128, 0, lds[0][3]);
  STG(Ab, m0,       0, lds[0][0]); STG(Ab, m0 + 128, 0, lds[0][1]);
  STG(Bb, n0,       1, lds[1][2]); STG(Bb, n0 + 128, 1, lds[1][3]);
  STG(Ab, m0,       1, lds[1][0]); STG(Ab, m0 + 128, 1, lds[1][1]);
  VMW(0);
  SCHEDB;
  BAR;
  SCHEDB;
  RD_B(bb0, 0);
  RD_A(a0, 0, 0);
  LGKM0;
  SCHEDB;

  for (int i = 0; i + 1 < (KT >> 1); ++i) {
    const int t2 = 2 * i + 2, t3 = 2 * i + 3;
    PH(0, 0, a0, bb0, RD_A(a1, 0, 1), STG(Bb, n0,       t2, lds[0][2]), VMW(8), 1);
    PH(0, 1, a0, bb0, (void)0,        STG(Bb, n0 + 128, t2, lds[0][3]), VMW(8), 1);
    PH(1, 0, a1, bb0, RD_B(bb1, 1),
       STG(Ab, m0, t2, lds[0][0]); STG(Ab, m0 + 128, t2, lds[0][1]),    VMW(8), 1);
    PH(1, 1, a1, bb0, RD_A(a0, 1, 0), (void)0,                          VMW(8), 1);
    PH(0, 0, a0, bb1, RD_A(a1, 1, 1), STG(Bb, n0,       t3, lds[1][2]), VMW(8), 1);
    PH(0, 1, a0, bb1, (void)0,        STG(Bb, n0 + 128, t3, lds[1][3]), VMW(8), 1);
    PH(1, 0, a1, bb1, RD_B(bb0, 0),
       STG(Ab, m0, t3, lds[1][0]); STG(Ab, m0 + 128, t3, lds[1][1]),    VMW(8), 1);
    PH(1, 1, a1, bb1, RD_A(a0, 0, 0), (void)0,                          VMW(8), 1);
  }
  // epilogue pair (tiles KT-2, KT-1): no stages; drain in two steps
  PH(0, 0, a0, bb0, RD_A(a1, 0, 1), (void)0, VMW(4), 1);
  PH(0, 1, a0, bb0, (void)0,        (void)0, VMW(0), 1);
  PH(1, 0, a1, bb0, RD_B(bb1, 1),   (void)0, (void)0, 0);
  PH(1, 1, a1, bb0, RD_A(a0, 1, 0), (void)0, (void)0, 0);
  PH(0, 0, a0, bb1, RD_A(a1, 1, 1), (void)0, (void)0, 0);
  PH(0, 1, a0, bb1, (void)0,        (void)0, (void)0, 0);
  PH(1, 0, a1, bb1, (void)0,        (void)0, (void)0, 0);
  PH(1, 1, a1, bb1, (void)0,        (void)0, (void)0, 0);

#undef PH
#undef RD_B
#undef RD_A
#undef STG

#pragma unroll
  for (int mf = 0; mf < 8; ++mf)
#pragma unroll
    for (int nf = 0; nf < 4; ++nf)
#pragma unroll
      for (int t = 0; t < 4; ++t) {
        int row = m0 + wm * 128 + mf * 16 + kg * 4 + t;
        int col = n0 + wn * 64 + nf * 16 + r15;
        if (out_f32)
          ((float*)Cout)[(size_t)row * N + col] = acc[mf][nf][t];
        else
          ((unsigned short*)Cout)[(size_t)row * N + col] = f2bf(acc[mf][nf][t]);
      }
}

// ---------------- flash attention (causal, GQA) ----------------
// 512 threads = 8 waves x 16 q-rows => 128 q-rows/block sharing one staged
// K/V tile (KVBLK=64). Double-buffered prefetch, one barrier per k-tile.
// Longest blocks dispatched first. Q pre-scaled by (1/sqrt(D))*log2(e).
// Q/K live in the fused QKV buffer: row stride QKVE elements.

__device__ __forceinline__ void sm_update(f32x4 sc[4], f32x4 o[8],
                                          float mrow[4], float lrow[4],
                                          bool diag, int qrow0, int kt,
                                          int r15, int kg, char* Pw) {
  if (diag) {
#pragma unroll
    for (int kf = 0; kf < 4; ++kf) {
      int kvg = kt * 64 + kf * 16 + r15;
#pragma unroll
      for (int t = 0; t < 4; ++t)
        if (kvg > qrow0 + kg * 4 + t) sc[kf][t] = -1e30f;
    }
  }
  float mx[4], sm[4];
#pragma unroll
  for (int t = 0; t < 4; ++t) {
    float v = fmaxf(fmaxf(sc[0][t], sc[1][t]), fmaxf(sc[2][t], sc[3][t]));
#pragma unroll
    for (int off = 1; off < 16; off <<= 1) v = fmaxf(v, __shfl_xor(v, off, 16));
    mx[t] = fmaxf(mrow[t], v);
    sm[t] = EXP2F(mrow[t] - mx[t]);
    mrow[t] = mx[t];
  }
#pragma unroll
  for (int kf = 0; kf < 4; ++kf)
#pragma unroll
    for (int t = 0; t < 4; ++t) sc[kf][t] = EXP2F(sc[kf][t] - mx[t]);
#pragma unroll
  for (int t = 0; t < 4; ++t) {
    float v = sc[0][t] + sc[1][t] + sc[2][t] + sc[3][t];
#pragma unroll
    for (int off = 1; off < 16; off <<= 1) v += __shfl_xor(v, off, 16);
    lrow[t] = lrow[t] * sm[t] + v;
  }
#pragma unroll
  for (int nf = 0; nf < 8; ++nf)
#pragma unroll
    for (int t = 0; t < 4; ++t) o[nf][t] *= sm[t];
  // P (C-layout) -> per-wave LDS (A-layout source), swizzled
#pragma unroll
  for (int kf = 0; kf < 4; ++kf)
#pragma unroll
    for (int t = 0; t < 4; ++t) {
      int r = kg * 4 + t, c = kf * 16 + r15;
      *(unsigned short*)(Pw + r * 128 + ((c * 2) ^ ((r & 7) << 4))) = f2bf(sc[kf][t]);
    }
}

__global__ __launch_bounds__(512, 4) void attn_kernel(
    const unsigned short* __restrict__ Q, const unsigned short* __restrict__ Kl,
    const unsigned short* __restrict__ Vt, unsigned short* __restrict__ AO) {
  __shared__ unsigned short Ks[2][64 * 128];   // [buf][kv][d], rows XOR-swizzled
  __shared__ unsigned short Vs[2][128 * 64];   // [buf][d][kv], rows XOR-swizzled
  __shared__ unsigned short Ps[8][16 * 64];    // per-wave P, swizzled
  const int tid = threadIdx.x, lane = tid & 63, wave = tid >> 6;
  const int h = blockIdx.x, b = blockIdx.z;
  const int qt = (QT - 1) - blockIdx.y;        // longest-first dispatch
  const int kvh = h >> 2;                      // G = 4
  const int r15 = lane & 15, kg = lane >> 4;
  const int qrow0 = qt * 128 + wave * 16;
  const int kmax = 2 * qt + 2;

  bf16x8 qf[4];
#pragma unroll
  for (int db = 0; db < 4; ++db)
    qf[db] = *(const bf16x8*)&Q[(size_t)(b * Sn + qrow0 + r15) * QKVE +
                                h * Dh + db * 32 + kg * 8];

  f32x4 o[8] = {};
  float mrow[4] = {-1e30f, -1e30f, -1e30f, -1e30f};
  float lrow[4] = {0.f, 0.f, 0.f, 0.f};

  const char* Kbase = (const char*)Kl + (size_t)(b * Sn) * (QKVE * 2) + kvh * 256;
  const char* Vbase = (const char*)Vt + (size_t)((b * NKV + kvh) * Dh) * (Sn * 2);

  auto stage = [&](int kt, int bi) {
#pragma unroll
    for (int c = 0; c < 2; ++c) {
      int f = (c * 512 + tid) * 16;
      int row = f >> 8, cb = f & 255;
      gl_lds16(Kbase + (size_t)(kt * 64 + row) * (QKVE * 2) + (cb ^ ((row & 7) << 4)),
               (char*)Ks[bi] + f);
    }
#pragma unroll
    for (int c = 0; c < 2; ++c) {
      int f = (c * 512 + tid) * 16;
      int row = f >> 7, cb = f & 127;
      gl_lds16(Vbase + (size_t)row * (Sn * 2) + kt * 128 + (cb ^ ((row & 7) << 4)),
               (char*)Vs[bi] + f);
    }
  };

  stage(0, 0);
  __syncthreads();

  for (int kt = 0; kt < kmax; ++kt) {
    const int cur = kt & 1;
    if (kt + 1 < kmax) stage(kt + 1, cur ^ 1);   // prefetch overlaps compute
    // skip tiles fully above the diagonal for this wave's strip (wave-uniform)
    if (kt * 64 <= qrow0 + 15) {
      const char* Kc = (const char*)Ks[cur];
      const char* Vc = (const char*)Vs[cur];
      f32x4 sc[4] = {};
      __builtin_amdgcn_s_setprio(1);
#pragma unroll
      for (int db = 0; db < 4; ++db) {
#pragma unroll
        for (int kf = 0; kf < 4; ++kf) {
          int krow = kf * 16 + r15;
          int cb = (db * 32 + kg * 8) * 2;
          bf16x8 kb = *(const bf16x8*)(Kc + krow * 256 + (cb ^ ((krow & 7) << 4)));
          sc[kf] = __builtin_amdgcn_mfma_f32_16x16x32_bf16(qf[db], kb, sc[kf], 0, 0, 0);
        }
      }
      __builtin_amdgcn_s_setprio(0);

      char* Pw = (char*)Ps[wave];
      bool diag = (kt * 64 + 63) > qrow0;        // tile touches the diagonal
      sm_update(sc, o, mrow, lrow, diag, qrow0, kt, r15, kg, Pw);

      __builtin_amdgcn_s_setprio(1);
#pragma unroll
      for (int ks = 0; ks < 2; ++ks) {
        bf16x8 pa = *(const bf16x8*)(Pw + r15 * 128 + ((kg * 16 + ks * 64) ^ ((r15 & 7) << 4)));
#pragma unroll
        for (int nf = 0; nf < 8; ++nf) {
          int vrow = nf * 16 + r15;
          int cb = (ks * 32 + kg * 8) * 2;
          bf16x8 vb = *(const bf16x8*)(Vc + vrow * 128 + (cb ^ ((vrow & 7) << 4)));
          o[nf] = __builtin_amdgcn_mfma_f32_16x16x32_bf16(pa, vb, o[nf], 0, 0, 0);
        }
      }
      __builtin_amdgcn_s_setprio(0);
    }
    __syncthreads();
  }

  float rinv[4];
#pragma unroll
  for (int t = 0; t < 4; ++t) rinv[t] = 1.0f / lrow[t];
#pragma unroll
  for (int nf = 0; nf < 8; ++nf)
#pragma unroll
    for (int t = 0; t < 4; ++t) {
      int srow = qrow0 + kg * 4 + t;
      AO[(size_t)(b * Sn + srow) * En + h * Dh + nf * 16 + r15] = f2bf(o[nf][t] * rinv[t]);
    }
}

// ---------------- launch ----------------

extern "C" void kernel_launch(void* const* d_in, const int* in_sizes, int n_in,
                              void* d_out, int out_size, void* d_ws, size_t ws_size,
                              hipStream_t stream) {
  const float* x  = (const float*)d_in[0];
  const float* Wq = (const float*)d_in[1];
  const float* Wk = (const float*)d_in[2];
  const float* Wv = (const float*)d_in[3];
  const float* Wo = (const float*)d_in[4];

  char* ws = (char*)d_ws;
  size_t off = 0;
  auto alloc = [&](size_t bytes) -> char* {
    char* p = ws + off;
    off += (bytes + 255) & ~(size_t)255;
    return p;
  };
  unsigned short* xb   = (unsigned short*)alloc((size_t)MT * En * 2);
  unsigned short* Wqkv = (unsigned short*)alloc((size_t)QKVE * En * 2); // rows: WqT|WkT|WvT
  unsigned short* WoT  = (unsigned short*)alloc((size_t)En * En * 2);
  unsigned short* Cqkv = (unsigned short*)alloc((size_t)MT * QKVE * 2); // [tok][Q|K|V]
  unsigned short* Vt   = (unsigned short*)alloc((size_t)MT * KVEn * 2);
  float2* cs           = (float2*)alloc((size_t)Sn * 64 * sizeof(float2));
  unsigned short* AO   = xb;   // alias: xb dead after the QKV projection

  cast_bf16_kernel<<<MT * (En / 4) / 256, 256, 0, stream>>>(x, xb, MT * En / 4);
  tcast_kernel<<<dim3(En / 32, En / 32), dim3(32, 32), 0, stream>>>(Wq, Wqkv, En, En);
  tcast_kernel<<<dim3(KVEn / 32, En / 32), dim3(32, 32), 0, stream>>>(
      Wk, Wqkv + (size_t)En * En, En, KVEn);
  tcast_kernel<<<dim3(KVEn / 32, En / 32), dim3(32, 32), 0, stream>>>(
      Wv, Wqkv + (size_t)(En + KVEn) * En, En, KVEn);
  tcast_kernel<<<dim3(En / 32, En / 32), dim3(32, 32), 0, stream>>>(Wo, WoT, En, En);
  rope_table_kernel<<<Sn * 64 / 256, 256, 0, stream>>>(cs);

  // fused QKV projection: [MT,4096] x [6144,4096]^T -> [MT,6144]
  gemm256_kernel<<<dim3(QKVE / 256, MT / 256), 512, 0, stream>>>(
      xb, Wqkv, Cqkv, MT, QKVE, En, 0);

  const float scl = 0.08838834764831845f * 1.4426950408889634f; // (1/sqrt(128))*log2(e)
  rope_kernel<<<dim3(MT, NH / 4), 256, 0, stream>>>(Cqkv, cs, QKVE, scl);
  rope_kernel<<<dim3(MT, NKV / 4), 256, 0, stream>>>(Cqkv + En, cs, QKVE, 1.0f);
  vtrans_kernel<<<dim3(Dh / 32, Sn / 32, Bn * NKV), dim3(32, 32), 0, stream>>>(
      Cqkv + En + KVEn, QKVE, Vt);

  attn_kernel<<<dim3(NH, QT, Bn), 512, 0, stream>>>(Cqkv, Cqkv + En, Vt, AO);

  gemm256_kernel<<<dim3(En / 256, MT / 256), 512, 0, stream>>>(
      AO, WoT, d_out, MT, En, En, 1);
}

// Round 9
// 1272.916 us; speedup vs baseline: 1.2506x; 1.2506x over previous
//
#include <hip/hip_runtime.h>
#include <stdint.h>
#include <math.h>

typedef short bf16x8 __attribute__((ext_vector_type(8)));
typedef float f32x4 __attribute__((ext_vector_type(4)));

#if __has_builtin(__builtin_amdgcn_exp2f)
#define EXP2F(x) __builtin_amdgcn_exp2f(x)
#else
#define EXP2F(x) exp2f(x)
#endif

static constexpr int Bn   = 2;
static constexpr int Sn   = 2048;
static constexpr int NH   = 32;
static constexpr int NKV  = 8;
static constexpr int Dh   = 128;
static constexpr int En   = NH * Dh;     // 4096
static constexpr int KVEn = NKV * Dh;    // 1024
static constexpr int QKVE = En + 2 * KVEn; // 6144 fused projection width
static constexpr int MT   = Bn * Sn;     // 4096 tokens
static constexpr int QT   = Sn / 128;    // 16 q-tiles (128 rows each)

__device__ __forceinline__ unsigned short f2bf(float f) {
  unsigned int u = __float_as_uint(f);
  u += 0x7FFFu + ((u >> 16) & 1u);
  return (unsigned short)(u >> 16);
}
__device__ __forceinline__ float bf2f(unsigned short h) {
  return __uint_as_float(((unsigned int)h) << 16);
}

typedef __attribute__((address_space(1))) void* gas_t;
typedef __attribute__((address_space(3))) void* las_t;
// async global->LDS, 16B per lane; lds dest must be wave-base + lane*16 (linear)
__device__ __forceinline__ void gl_lds16(const void* g, void* l) {
  __builtin_amdgcn_global_load_lds((gas_t)(uintptr_t)g, (las_t)(uint32_t)(uintptr_t)l,
                                   16, 0, 0);
}

#define VMW(n)  asm volatile("s_waitcnt vmcnt(" #n ")" ::: "memory")
#define LGKM0   asm volatile("s_waitcnt lgkmcnt(0)" ::: "memory")
#define SCHEDB  __builtin_amdgcn_sched_barrier(0)
#define BAR     __builtin_amdgcn_s_barrier()

// ---------------- pre/post passes ----------------

__global__ void cast_bf16_kernel(const float* __restrict__ x,
                                 unsigned short* __restrict__ y, int n4) {
  int i = blockIdx.x * 256 + threadIdx.x;
  if (i >= n4) return;
  float4 v = ((const float4*)x)[i];
  ushort4 o;
  o.x = f2bf(v.x); o.y = f2bf(v.y); o.z = f2bf(v.z); o.w = f2bf(v.w);
  ((ushort4*)y)[i] = o;
}

// W [R][C] f32 -> WT [C][R] bf16 (tiled, coalesced both sides)
__global__ void tcast_kernel(const float* __restrict__ W,
                             unsigned short* __restrict__ WT, int R, int C) {
  __shared__ float t[32][33];
  int tx = threadIdx.x, ty = threadIdx.y;
  int c = blockIdx.x * 32 + tx, r = blockIdx.y * 32 + ty;
  t[ty][tx] = W[(size_t)r * C + c];
  __syncthreads();
  int ro = blockIdx.x * 32 + ty, co = blockIdx.y * 32 + tx;
  WT[(size_t)ro * R + co] = f2bf(t[tx][ty]);
}

__global__ void rope_table_kernel(float2* __restrict__ cs) {
  int i = blockIdx.x * 256 + threadIdx.x;   // i < Sn*64
  int s = i >> 6, d = i & 63;
  float inv = powf(10000.0f, -(float)d * (1.0f / 64.0f));
  float a = (float)s * inv;
  cs[i] = make_float2(cosf(a), sinf(a));
}

// in-place RoPE on [MT][rowstride] starting at column 0 of q; pairs (d, d+64)
__global__ void rope_kernel(unsigned short* __restrict__ q,
                            const float2* __restrict__ cs, int rowstride, float scl) {
  int row = blockIdx.x;
  int s = row & (Sn - 1);
  int hl = threadIdx.x >> 6, d = threadIdx.x & 63;
  int h = blockIdx.y * 4 + hl;
  size_t base = (size_t)row * rowstride + (size_t)h * Dh + d;
  float2 c = cs[s * 64 + d];
  float x0 = bf2f(q[base]), x1 = bf2f(q[base + 64]);
  q[base]      = f2bf((x0 * c.x - x1 * c.y) * scl);
  q[base + 64] = f2bf((x1 * c.x + x0 * c.y) * scl);
}

// V (strided rows) -> Vt [B][KV][D][S]  (d-major so PV B-frags are k-contiguous)
__global__ void vtrans_kernel(const unsigned short* __restrict__ V, int rowstride,
                              unsigned short* __restrict__ Vt) {
  __shared__ unsigned short t[32][33];
  int bk = blockIdx.z;                 // b*NKV+kv
  int b = bk >> 3, kv = bk & 7;
  int d = blockIdx.x * 32 + threadIdx.x;
  int s = blockIdx.y * 32 + threadIdx.y;
  t[threadIdx.y][threadIdx.x] = V[(size_t)(b * Sn + s) * rowstride + kv * Dh + d];
  __syncthreads();
  int dd = blockIdx.x * 32 + threadIdx.y;
  int so = blockIdx.y * 32 + threadIdx.x;
  Vt[((size_t)bk * Dh + dd) * Sn + so] = t[threadIdx.x][threadIdx.y];
}

// ---------------- GEMM 256x256, 8-phase quadrant + read-ahead frags ----------
// R4 structure: phase = C-quadrant 128x128, 8 waves (2x4, 64x32 piece each),
// 16 MFMA/phase; stage 1 half-tile/phase; vmcnt ladder {6,10,-,8} (slot-landing
// proof preserved). Read-ahead: each phase, after its VMW, issues the ds_reads
// for the NEXT phase's new fragments (tail-reads) into an alternate A-bank;
// lgkmcnt(0) sits at phase top, so ds_read latency hides under the previous
// phase's MFMA. EPILOGUE FIX (R7 bug): A1/B1 of tile KT-1 must still be staged
// (E1/E2), with ladder VMW(6)/-/-/VMW(4)/VMW(0): every epilogue tail read
// verified to land before use. KT even, >= 4.

__global__ __launch_bounds__(512, 2) void gemm256_kernel(
    const unsigned short* __restrict__ A, const unsigned short* __restrict__ BT,
    void* __restrict__ Cout, int M, int N, int K, int out_f32) {
  __shared__ unsigned short lds[2][4][128 * 64];  // [buf][A0,A1,B0,B1]
  const int tid = threadIdx.x;
  const int lane = tid & 63, wave = tid >> 6;
  const int r15 = lane & 15, kg = lane >> 4;
  const int wr = wave >> 2, wc = wave & 3;        // wave pos within quadrant
  const int m0 = blockIdx.y * 256, n0 = blockIdx.x * 256;
  const char* Ab = (const char*)A;
  const char* Bb = (const char*)BT;
  const int KT = K >> 6;

  f32x4 acc[2][2][4][2] = {};   // [mh][nh][mf][nf]
  bf16x8 aA[4][2], aB[4][2];    // A frag banks (alternate per 2 phases)
  bf16x8 br[2][2][2];           // B frags [nh][nf][ks]

#define STAGE_H(SRC, ROW0, KT_, SLOT)                                         \
  do {                                                                        \
    _Pragma("unroll") for (int ld = 0; ld < 2; ++ld) {                        \
      int _f = (ld * 512 + tid) * 16;                                         \
      int _row = _f >> 7, _cb = _f & 127;                                     \
      gl_lds16(SRC + ((size_t)((ROW0) + _row) * K + (size_t)(KT_) * 64) * 2 + \
                   (_cb ^ ((_row & 7) << 4)),                                 \
               (char*)(SLOT) + _f);                                           \
    }                                                                         \
  } while (0)

#define RD_A(DST, BUF, MQ)                                                    \
  do {                                                                        \
    const char* _as = (const char*)lds[BUF][MQ];                              \
    _Pragma("unroll") for (int mf = 0; mf < 4; ++mf) {                        \
      int _r = wr * 64 + mf * 16 + r15;                                       \
      int _sw = (_r & 7) << 4;                                                \
      DST[mf][0] = *(const bf16x8*)(_as + _r * 128 + ((kg * 16) ^ _sw));      \
      DST[mf][1] = *(const bf16x8*)(_as + _r * 128 + ((64 + kg * 16) ^ _sw)); \
    }                                                                         \
  } while (0)

#define RD_B(NHI, BUF)                                                        \
  do {                                                                        \
    const char* _bs = (const char*)lds[BUF][2 + (NHI)];                       \
    _Pragma("unroll") for (int nf = 0; nf < 2; ++nf) {                        \
      int _r = wc * 32 + nf * 16 + r15;                                       \
      int _sw = (_r & 7) << 4;                                                \
      br[NHI][nf][0] = *(const bf16x8*)(_bs + _r * 128 + ((kg * 16) ^ _sw));  \
      br[NHI][nf][1] =                                                        \
          *(const bf16x8*)(_bs + _r * 128 + ((64 + kg * 16) ^ _sw));          \
    }                                                                         \
  } while (0)

  // phase: stage -> VMW (slot landing) -> LGKM0 (prev tail-reads done) ->
  //        tail-reads for next phase -> MFMA -> barrier
#define GPHASE(MH, NH, ABANK, STAGE_STMT, WAIT_STMT, TAIL_STMT)               \
  do {                                                                        \
    STAGE_STMT;                                                               \
    WAIT_STMT;                                                                \
    LGKM0;                                                                    \
    SCHEDB;                                                                   \
    TAIL_STMT;                                                                \
    __builtin_amdgcn_s_setprio(1);                                            \
    _Pragma("unroll") for (int mf = 0; mf < 4; ++mf)                          \
      _Pragma("unroll") for (int n2 = 0; n2 < 2; ++n2) {                      \
        acc[MH][NH][mf][n2] = __builtin_amdgcn_mfma_f32_16x16x32_bf16(        \
            ABANK[mf][0], br[NH][n2][0], acc[MH][NH][mf][n2], 0, 0, 0);       \
        acc[MH][NH][mf][n2] = __builtin_amdgcn_mfma_f32_16x16x32_bf16(        \
            ABANK[mf][1], br[NH][n2][1], acc[MH][NH][mf][n2], 0, 0, 0);       \
      }                                                                       \
    __builtin_amdgcn_s_setprio(0);                                            \
    SCHEDB;                                                                   \
    BAR;                                                                      \
    SCHEDB;                                                                   \
  } while (0)

  // prologue: A0,B0,A1,B1 of tile0; A0,B0 of tile1 (12 loads). VMW(8) ->
  // 4 oldest (A0,B0 tile0) landed; pre-read them into aA/br[0].
  STAGE_H(Ab, m0,       0, lds[0][0]);
  STAGE_H(Bb, n0,       0, lds[0][2]);
  STAGE_H(Ab, m0 + 128, 0, lds[0][1]);
  STAGE_H(Bb, n0 + 128, 0, lds[0][3]);
  STAGE_H(Ab, m0,       1, lds[1][0]);
  STAGE_H(Bb, n0,       1, lds[1][2]);
  VMW(8);
  SCHEDB;
  BAR;
  SCHEDB;
  RD_A(aA, 0, 0);
  RD_B(0, 0);

  for (int i = 0; i + 1 < (KT >> 1); ++i) {
    const int t2 = 2 * i + 2, t3 = 2 * i + 3;
    GPHASE(0, 0, aA, STAGE_H(Ab, m0 + 128, t2 - 1, lds[1][1]), VMW(6),  RD_B(1, 0));
    GPHASE(0, 1, aA, STAGE_H(Bb, n0 + 128, t2 - 1, lds[1][3]), VMW(10), RD_A(aB, 0, 1));
    GPHASE(1, 0, aB, STAGE_H(Ab, m0,       t2,     lds[0][0]), (void)0, (void)0);
    GPHASE(1, 1, aB, STAGE_H(Bb, n0,       t2,     lds[0][2]), VMW(8),
           RD_A(aA, 1, 0); RD_B(0, 1));
    GPHASE(0, 0, aA, STAGE_H(Ab, m0 + 128, t2,     lds[0][1]), VMW(6),  RD_B(1, 1));
    GPHASE(0, 1, aA, STAGE_H(Bb, n0 + 128, t2,     lds[0][3]), VMW(10), RD_A(aB, 1, 1));
    GPHASE(1, 0, aB, STAGE_H(Ab, m0,       t3,     lds[1][0]), (void)0, (void)0);
    GPHASE(1, 1, aB, STAGE_H(Bb, n0,       t3,     lds[1][2]), VMW(8),
           RD_A(aA, 0, 0); RD_B(0, 0));
  }
  // epilogue: computing tiles KT-2 (buf0), KT-1 (buf1). A1/B1 of KT-1 MUST
  // still be staged (E1/E2 — R7 omitted these: stale-data bug). Ladder:
  // entering outstanding = 8 (A1,B1 KT-2; A0,B0 KT-1 from last iter).
  // E1 VMW(6) lands A1,B1 KT-2; E4 VMW(4) lands A0,B0 KT-1; E5 VMW(0)
  // lands E1/E2's stages (A1,B1 KT-1) for the E5/E6 tails.
  GPHASE(0, 0, aA, STAGE_H(Ab, m0 + 128, KT - 1, lds[1][1]), VMW(6), RD_B(1, 0));
  GPHASE(0, 1, aA, STAGE_H(Bb, n0 + 128, KT - 1, lds[1][3]), (void)0, RD_A(aB, 0, 1));
  GPHASE(1, 0, aB, (void)0, (void)0, (void)0);
  GPHASE(1, 1, aB, (void)0, VMW(4),  RD_A(aA, 1, 0); RD_B(0, 1));
  GPHASE(0, 0, aA, (void)0, VMW(0),  RD_B(1, 1));
  GPHASE(0, 1, aA, (void)0, (void)0, RD_A(aB, 1, 1));
  GPHASE(1, 0, aB, (void)0, (void)0, (void)0);
  GPHASE(1, 1, aB, (void)0, (void)0, (void)0);

#undef GPHASE
#undef RD_B
#undef RD_A
#undef STAGE_H

#pragma unroll
  for (int mh = 0; mh < 2; ++mh)
#pragma unroll
    for (int nh = 0; nh < 2; ++nh)
#pragma unroll
      for (int mf = 0; mf < 4; ++mf)
#pragma unroll
        for (int nf = 0; nf < 2; ++nf)
#pragma unroll
          for (int t = 0; t < 4; ++t) {
            int row = m0 + mh * 128 + wr * 64 + mf * 16 + kg * 4 + t;
            int col = n0 + nh * 128 + wc * 32 + nf * 16 + r15;
            if (out_f32)
              ((float*)Cout)[(size_t)row * N + col] = acc[mh][nh][mf][nf][t];
            else
              ((unsigned short*)Cout)[(size_t)row * N + col] =
                  f2bf(acc[mh][nh][mf][nf][t]);
          }
}

// ---------------- flash attention (causal, GQA) ----------------
// 512 threads = 8 waves x 16 q-rows => 128 q-rows/block sharing one staged
// K/V tile (KVBLK=64). Double-buffered prefetch, one barrier per k-tile.
// Longest blocks dispatched first. Q pre-scaled by (1/sqrt(D))*log2(e).
// Q/K live in the fused QKV buffer: row stride QKVE elements.

__device__ __forceinline__ void sm_update(f32x4 sc[4], f32x4 o[8],
                                          float mrow[4], float lrow[4],
                                          bool diag, int qrow0, int kt,
                                          int r15, int kg, char* Pw) {
  if (diag) {
#pragma unroll
    for (int kf = 0; kf < 4; ++kf) {
      int kvg = kt * 64 + kf * 16 + r15;
#pragma unroll
      for (int t = 0; t < 4; ++t)
        if (kvg > qrow0 + kg * 4 + t) sc[kf][t] = -1e30f;
    }
  }
  float mx[4], sm[4];
#pragma unroll
  for (int t = 0; t < 4; ++t) {
    float v = fmaxf(fmaxf(sc[0][t], sc[1][t]), fmaxf(sc[2][t], sc[3][t]));
#pragma unroll
    for (int off = 1; off < 16; off <<= 1) v = fmaxf(v, __shfl_xor(v, off, 16));
    mx[t] = fmaxf(mrow[t], v);
    sm[t] = EXP2F(mrow[t] - mx[t]);
    mrow[t] = mx[t];
  }
#pragma unroll
  for (int kf = 0; kf < 4; ++kf)
#pragma unroll
    for (int t = 0; t < 4; ++t) sc[kf][t] = EXP2F(sc[kf][t] - mx[t]);
#pragma unroll
  for (int t = 0; t < 4; ++t) {
    float v = sc[0][t] + sc[1][t] + sc[2][t] + sc[3][t];
#pragma unroll
    for (int off = 1; off < 16; off <<= 1) v += __shfl_xor(v, off, 16);
    lrow[t] = lrow[t] * sm[t] + v;
  }
#pragma unroll
  for (int nf = 0; nf < 8; ++nf)
#pragma unroll
    for (int t = 0; t < 4; ++t) o[nf][t] *= sm[t];
  // P (C-layout) -> per-wave LDS (A-layout source), swizzled
#pragma unroll
  for (int kf = 0; kf < 4; ++kf)
#pragma unroll
    for (int t = 0; t < 4; ++t) {
      int r = kg * 4 + t, c = kf * 16 + r15;
      *(unsigned short*)(Pw + r * 128 + ((c * 2) ^ ((r & 7) << 4))) = f2bf(sc[kf][t]);
    }
}

__global__ __launch_bounds__(512, 4) void attn_kernel(
    const unsigned short* __restrict__ Q, const unsigned short* __restrict__ Kl,
    const unsigned short* __restrict__ Vt, unsigned short* __restrict__ AO) {
  __shared__ unsigned short Ks[2][64 * 128];   // [buf][kv][d], rows XOR-swizzled
  __shared__ unsigned short Vs[2][128 * 64];   // [buf][d][kv], rows XOR-swizzled
  __shared__ unsigned short Ps[8][16 * 64];    // per-wave P, swizzled
  const int tid = threadIdx.x, lane = tid & 63, wave = tid >> 6;
  const int h = blockIdx.x, b = blockIdx.z;
  const int qt = (QT - 1) - blockIdx.y;        // longest-first dispatch
  const int kvh = h >> 2;                      // G = 4
  const int r15 = lane & 15, kg = lane >> 4;
  const int qrow0 = qt * 128 + wave * 16;
  const int kmax = 2 * qt + 2;

  bf16x8 qf[4];
#pragma unroll
  for (int db = 0; db < 4; ++db)
    qf[db] = *(const bf16x8*)&Q[(size_t)(b * Sn + qrow0 + r15) * QKVE +
                                h * Dh + db * 32 + kg * 8];

  f32x4 o[8] = {};
  float mrow[4] = {-1e30f, -1e30f, -1e30f, -1e30f};
  float lrow[4] = {0.f, 0.f, 0.f, 0.f};

  const char* Kbase = (const char*)Kl + (size_t)(b * Sn) * (QKVE * 2) + kvh * 256;
  const char* Vbase = (const char*)Vt + (size_t)((b * NKV + kvh) * Dh) * (Sn * 2);

  auto stage = [&](int kt, int bi) {
#pragma unroll
    for (int c = 0; c < 2; ++c) {
      int f = (c * 512 + tid) * 16;
      int row = f >> 8, cb = f & 255;
      gl_lds16(Kbase + (size_t)(kt * 64 + row) * (QKVE * 2) + (cb ^ ((row & 7) << 4)),
               (char*)Ks[bi] + f);
    }
#pragma unroll
    for (int c = 0; c < 2; ++c) {
      int f = (c * 512 + tid) * 16;
      int row = f >> 7, cb = f & 127;
      gl_lds16(Vbase + (size_t)row * (Sn * 2) + kt * 128 + (cb ^ ((row & 7) << 4)),
               (char*)Vs[bi] + f);
    }
  };

  stage(0, 0);
  __syncthreads();

  for (int kt = 0; kt < kmax; ++kt) {
    const int cur = kt & 1;
    if (kt + 1 < kmax) stage(kt + 1, cur ^ 1);   // prefetch overlaps compute
    // skip tiles fully above the diagonal for this wave's strip (wave-uniform)
    if (kt * 64 <= qrow0 + 15) {
      const char* Kc = (const char*)Ks[cur];
      const char* Vc = (const char*)Vs[cur];
      f32x4 sc[4] = {};
      __builtin_amdgcn_s_setprio(1);
#pragma unroll
      for (int db = 0; db < 4; ++db) {
#pragma unroll
        for (int kf = 0; kf < 4; ++kf) {
          int krow = kf * 16 + r15;
          int cb = (db * 32 + kg * 8) * 2;
          bf16x8 kb = *(const bf16x8*)(Kc + krow * 256 + (cb ^ ((krow & 7) << 4)));
          sc[kf] = __builtin_amdgcn_mfma_f32_16x16x32_bf16(qf[db], kb, sc[kf], 0, 0, 0);
        }
      }
      __builtin_amdgcn_s_setprio(0);

      char* Pw = (char*)Ps[wave];
      bool diag = (kt * 64 + 63) > qrow0;        // tile touches the diagonal
      sm_update(sc, o, mrow, lrow, diag, qrow0, kt, r15, kg, Pw);

      __builtin_amdgcn_s_setprio(1);
#pragma unroll
      for (int ks = 0; ks < 2; ++ks) {
        bf16x8 pa = *(const bf16x8*)(Pw + r15 * 128 + ((kg * 16 + ks * 64) ^ ((r15 & 7) << 4)));
#pragma unroll
        for (int nf = 0; nf < 8; ++nf) {
          int vrow = nf * 16 + r15;
          int cb = (ks * 32 + kg * 8) * 2;
          bf16x8 vb = *(const bf16x8*)(Vc + vrow * 128 + (cb ^ ((vrow & 7) << 4)));
          o[nf] = __builtin_amdgcn_mfma_f32_16x16x32_bf16(pa, vb, o[nf], 0, 0, 0);
        }
      }
      __builtin_amdgcn_s_setprio(0);
    }
    __syncthreads();
  }

  float rinv[4];
#pragma unroll
  for (int t = 0; t < 4; ++t) rinv[t] = 1.0f / lrow[t];
#pragma unroll
  for (int nf = 0; nf < 8; ++nf)
#pragma unroll
    for (int t = 0; t < 4; ++t) {
      int srow = qrow0 + kg * 4 + t;
      AO[(size_t)(b * Sn + srow) * En + h * Dh + nf * 16 + r15] = f2bf(o[nf][t] * rinv[t]);
    }
}

// ---------------- launch ----------------

extern "C" void kernel_launch(void* const* d_in, const int* in_sizes, int n_in,
                              void* d_out, int out_size, void* d_ws, size_t ws_size,
                              hipStream_t stream) {
  const float* x  = (const float*)d_in[0];
  const float* Wq = (const float*)d_in[1];
  const float* Wk = (const float*)d_in[2];
  const float* Wv = (const float*)d_in[3];
  const float* Wo = (const float*)d_in[4];

  char* ws = (char*)d_ws;
  size_t off = 0;
  auto alloc = [&](size_t bytes) -> char* {
    char* p = ws + off;
    off += (bytes + 255) & ~(size_t)255;
    return p;
  };
  unsigned short* xb   = (unsigned short*)alloc((size_t)MT * En * 2);
  unsigned short* Wqkv = (unsigned short*)alloc((size_t)QKVE * En * 2); // rows: WqT|WkT|WvT
  unsigned short* WoT  = (unsigned short*)alloc((size_t)En * En * 2);
  unsigned short* Cqkv = (unsigned short*)alloc((size_t)MT * QKVE * 2); // [tok][Q|K|V]
  unsigned short* Vt   = (unsigned short*)alloc((size_t)MT * KVEn * 2);
  float2* cs           = (float2*)alloc((size_t)Sn * 64 * sizeof(float2));
  unsigned short* AO   = xb;   // alias: xb dead after the QKV projection

  cast_bf16_kernel<<<MT * (En / 4) / 256, 256, 0, stream>>>(x, xb, MT * En / 4);
  tcast_kernel<<<dim3(En / 32, En / 32), dim3(32, 32), 0, stream>>>(Wq, Wqkv, En, En);
  tcast_kernel<<<dim3(KVEn / 32, En / 32), dim3(32, 32), 0, stream>>>(
      Wk, Wqkv + (size_t)En * En, En, KVEn);
  tcast_kernel<<<dim3(KVEn / 32, En / 32), dim3(32, 32), 0, stream>>>(
      Wv, Wqkv + (size_t)(En + KVEn) * En, En, KVEn);
  tcast_kernel<<<dim3(En / 32, En / 32), dim3(32, 32), 0, stream>>>(Wo, WoT, En, En);
  rope_table_kernel<<<Sn * 64 / 256, 256, 0, stream>>>(cs);

  // fused QKV projection: [MT,4096] x [6144,4096]^T -> [MT,6144]
  gemm256_kernel<<<dim3(QKVE / 256, MT / 256), 512, 0, stream>>>(
      xb, Wqkv, Cqkv, MT, QKVE, En, 0);

  const float scl = 0.08838834764831845f * 1.4426950408889634f; // (1/sqrt(128))*log2(e)
  rope_kernel<<<dim3(MT, NH / 4), 256, 0, stream>>>(Cqkv, cs, QKVE, scl);
  rope_kernel<<<dim3(MT, NKV / 4), 256, 0, stream>>>(Cqkv + En, cs, QKVE, 1.0f);
  vtrans_kernel<<<dim3(Dh / 32, Sn / 32, Bn * NKV), dim3(32, 32), 0, stream>>>(
      Cqkv + En + KVEn, QKVE, Vt);

  attn_kernel<<<dim3(NH, QT, Bn), 512, 0, stream>>>(Cqkv, Cqkv + En, Vt, AO);

  gemm256_kernel<<<dim3(En / 256, MT / 256), 512, 0, stream>>>(
      AO, WoT, d_out, MT, En, En, 1);
}

// Round 10
// 615.847 us; speedup vs baseline: 2.5848x; 2.0669x over previous
//
#include <hip/hip_runtime.h>
#include <stdint.h>
#include <math.h>

typedef short bf16x8 __attribute__((ext_vector_type(8)));
typedef float f32x4 __attribute__((ext_vector_type(4)));

#if __has_builtin(__builtin_amdgcn_exp2f)
#define EXP2F(x) __builtin_amdgcn_exp2f(x)
#else
#define EXP2F(x) exp2f(x)
#endif

static constexpr int Bn   = 2;
static constexpr int Sn   = 2048;
static constexpr int NH   = 32;
static constexpr int NKV  = 8;
static constexpr int Dh   = 128;
static constexpr int En   = NH * Dh;     // 4096
static constexpr int KVEn = NKV * Dh;    // 1024
static constexpr int QKVE = En + 2 * KVEn; // 6144 fused projection width
static constexpr int MT   = Bn * Sn;     // 4096 tokens
static constexpr int QT   = Sn / 128;    // 16 q-tiles (128 rows each)

__device__ __forceinline__ unsigned short f2bf(float f) {
  unsigned int u = __float_as_uint(f);
  u += 0x7FFFu + ((u >> 16) & 1u);
  return (unsigned short)(u >> 16);
}
__device__ __forceinline__ float bf2f(unsigned short h) {
  return __uint_as_float(((unsigned int)h) << 16);
}

typedef __attribute__((address_space(1))) void* gas_t;
typedef __attribute__((address_space(3))) void* las_t;
// async global->LDS, 16B per lane; lds dest must be wave-base + lane*16 (linear)
__device__ __forceinline__ void gl_lds16(const void* g, void* l) {
  __builtin_amdgcn_global_load_lds((gas_t)(uintptr_t)g, (las_t)(uint32_t)(uintptr_t)l,
                                   16, 0, 0);
}

#define VMW(n)  asm volatile("s_waitcnt vmcnt(" #n ")" ::: "memory")
#define LGKM0   asm volatile("s_waitcnt lgkmcnt(0)" ::: "memory")
#define SCHEDB  __builtin_amdgcn_sched_barrier(0)
#define BAR     __builtin_amdgcn_s_barrier()

// ---------------- pre/post passes ----------------

__global__ void cast_bf16_kernel(const float* __restrict__ x,
                                 unsigned short* __restrict__ y, int n4) {
  int i = blockIdx.x * 256 + threadIdx.x;
  if (i >= n4) return;
  float4 v = ((const float4*)x)[i];
  ushort4 o;
  o.x = f2bf(v.x); o.y = f2bf(v.y); o.z = f2bf(v.z); o.w = f2bf(v.w);
  ((ushort4*)y)[i] = o;
}

// W [R][C] f32 -> WT [C][R] bf16 (tiled, coalesced both sides)
__global__ void tcast_kernel(const float* __restrict__ W,
                             unsigned short* __restrict__ WT, int R, int C) {
  __shared__ float t[32][33];
  int tx = threadIdx.x, ty = threadIdx.y;
  int c = blockIdx.x * 32 + tx, r = blockIdx.y * 32 + ty;
  t[ty][tx] = W[(size_t)r * C + c];
  __syncthreads();
  int ro = blockIdx.x * 32 + ty, co = blockIdx.y * 32 + tx;
  WT[(size_t)ro * R + co] = f2bf(t[tx][ty]);
}

__global__ void rope_table_kernel(float2* __restrict__ cs) {
  int i = blockIdx.x * 256 + threadIdx.x;   // i < Sn*64
  int s = i >> 6, d = i & 63;
  float inv = powf(10000.0f, -(float)d * (1.0f / 64.0f));
  float a = (float)s * inv;
  cs[i] = make_float2(cosf(a), sinf(a));
}

// in-place RoPE on [MT][rowstride] starting at column 0 of q; pairs (d, d+64)
__global__ void rope_kernel(unsigned short* __restrict__ q,
                            const float2* __restrict__ cs, int rowstride, float scl) {
  int row = blockIdx.x;
  int s = row & (Sn - 1);
  int hl = threadIdx.x >> 6, d = threadIdx.x & 63;
  int h = blockIdx.y * 4 + hl;
  size_t base = (size_t)row * rowstride + (size_t)h * Dh + d;
  float2 c = cs[s * 64 + d];
  float x0 = bf2f(q[base]), x1 = bf2f(q[base + 64]);
  q[base]      = f2bf((x0 * c.x - x1 * c.y) * scl);
  q[base + 64] = f2bf((x1 * c.x + x0 * c.y) * scl);
}

// V (strided rows) -> Vt [B][KV][D][S]  (d-major so PV B-frags are k-contiguous)
__global__ void vtrans_kernel(const unsigned short* __restrict__ V, int rowstride,
                              unsigned short* __restrict__ Vt) {
  __shared__ unsigned short t[32][33];
  int bk = blockIdx.z;                 // b*NKV+kv
  int b = bk >> 3, kv = bk & 7;
  int d = blockIdx.x * 32 + threadIdx.x;
  int s = blockIdx.y * 32 + threadIdx.y;
  t[threadIdx.y][threadIdx.x] = V[(size_t)(b * Sn + s) * rowstride + kv * Dh + d];
  __syncthreads();
  int dd = blockIdx.x * 32 + threadIdx.y;
  int so = blockIdx.y * 32 + threadIdx.x;
  Vt[((size_t)bk * Dh + dd) * Sn + so] = t[threadIdx.x][threadIdx.y];
}

// ---------------- GEMM 256x256, true 8-phase (R4-exact, session best) --------
// A[M,K] bf16, BT[N,K] bf16 -> C[M,N]. 512 thr = 8 waves. BK=64.
// Phase = block-level C-quadrant 128x128 (all 8 waves remapped into it, 2x4,
// 64x32 piece each, 16 MFMA). 8 phases process 2 K-tiles; each phase stages
// exactly one half-tile (128x64, 2 gl_lds/thread). buf0 = even K-tiles,
// buf1 = odd. Stage order: A1(k+1),B1(k+1),A0(k+2),B0(k+2),A1(k+2),B1(k+2),
// A0(k+3),B0(k+3). Counted vmcnt {6,10,-,8} from slot/landing proof; never
// drained to 0 in the main loop. Rows XOR-swizzled (row&7)<<4, same involution
// on global source and ds_read. KT even, >= 4.
// NOTE (R5-R8 post-mortems): T1 XCD remap, 4-bank frag pipeline, and tail-read
// read-ahead all regressed vs this configuration — do not reapply without new
// counter evidence.

__global__ __launch_bounds__(512, 2) void gemm256_kernel(
    const unsigned short* __restrict__ A, const unsigned short* __restrict__ BT,
    void* __restrict__ Cout, int M, int N, int K, int out_f32) {
  __shared__ unsigned short lds[2][4][128 * 64];  // [buf][A0,A1,B0,B1]
  const int tid = threadIdx.x;
  const int lane = tid & 63, wave = tid >> 6;
  const int r15 = lane & 15, kg = lane >> 4;
  const int wr = wave >> 2, wc = wave & 3;        // wave pos within quadrant
  const int m0 = blockIdx.y * 256, n0 = blockIdx.x * 256;
  const char* Ab = (const char*)A;
  const char* Bb = (const char*)BT;
  const int KT = K >> 6;

  f32x4 acc[2][2][4][2] = {};   // [mh][nh][mf][nf]
  bf16x8 ar[4][2];              // current quadrant's A frags [mf][ks]
  bf16x8 br[2][2][2];           // persistent B frags [nh][nf][ks]

#define STAGE_H(SRC, ROW0, KT_, SLOT)                                         \
  do {                                                                        \
    _Pragma("unroll") for (int ld = 0; ld < 2; ++ld) {                        \
      int _f = (ld * 512 + tid) * 16;                                         \
      int _row = _f >> 7, _cb = _f & 127;                                     \
      gl_lds16(SRC + ((size_t)((ROW0) + _row) * K + (size_t)(KT_) * 64) * 2 + \
                   (_cb ^ ((_row & 7) << 4)),                                 \
               (char*)(SLOT) + _f);                                           \
    }                                                                         \
  } while (0)

#define GPHASE(MH, NH, BUF, DO_LDA, DO_LDB, STAGE_STMT, WAIT_STMT)            \
  do {                                                                        \
    if (DO_LDA) {                                                             \
      const char* _as = (const char*)lds[BUF][MH];                            \
      _Pragma("unroll") for (int mf = 0; mf < 4; ++mf) {                      \
        int _r = wr * 64 + mf * 16 + r15;                                     \
        int _sw = (_r & 7) << 4;                                              \
        ar[mf][0] = *(const bf16x8*)(_as + _r * 128 + ((kg * 16) ^ _sw));     \
        ar[mf][1] = *(const bf16x8*)(_as + _r * 128 + ((64 + kg * 16) ^ _sw));\
      }                                                                       \
    }                                                                         \
    if (DO_LDB) {                                                             \
      const char* _bs = (const char*)lds[BUF][2 + NH];                        \
      _Pragma("unroll") for (int nf = 0; nf < 2; ++nf) {                      \
        int _r = wc * 32 + nf * 16 + r15;                                     \
        int _sw = (_r & 7) << 4;                                              \
        br[NH][nf][0] =                                                       \
            *(const bf16x8*)(_bs + _r * 128 + ((kg * 16) ^ _sw));             \
        br[NH][nf][1] =                                                       \
            *(const bf16x8*)(_bs + _r * 128 + ((64 + kg * 16) ^ _sw));        \
      }                                                                       \
    }                                                                         \
    STAGE_STMT;                                                               \
    BAR;                                                                      \
    if ((DO_LDA) || (DO_LDB)) { LGKM0; }                                      \
    SCHEDB;                                                                   \
    __builtin_amdgcn_s_setprio(1);                                            \
    _Pragma("unroll") for (int mf = 0; mf < 4; ++mf)                          \
      _Pragma("unroll") for (int n2 = 0; n2 < 2; ++n2) {                      \
        acc[MH][NH][mf][n2] = __builtin_amdgcn_mfma_f32_16x16x32_bf16(        \
            ar[mf][0], br[NH][n2][0], acc[MH][NH][mf][n2], 0, 0, 0);          \
        acc[MH][NH][mf][n2] = __builtin_amdgcn_mfma_f32_16x16x32_bf16(        \
            ar[mf][1], br[NH][n2][1], acc[MH][NH][mf][n2], 0, 0, 0);          \
      }                                                                       \
    __builtin_amdgcn_s_setprio(0);                                            \
    SCHEDB;                                                                   \
    WAIT_STMT;                                                                \
    BAR;                                                                      \
    SCHEDB;                                                                   \
  } while (0)

  // prologue: halves in steady-state order A0(0),B0(0),A1(0),B1(0),A0(1),B0(1)
  STAGE_H(Ab, m0,       0, lds[0][0]);
  STAGE_H(Bb, n0,       0, lds[0][2]);
  STAGE_H(Ab, m0 + 128, 0, lds[0][1]);
  STAGE_H(Bb, n0 + 128, 0, lds[0][3]);
  STAGE_H(Ab, m0,       1, lds[1][0]);
  STAGE_H(Bb, n0,       1, lds[1][2]);
  VMW(8);
  SCHEDB;
  BAR;
  SCHEDB;

  for (int k = 0; k + 2 < KT; k += 2) {
    GPHASE(0, 0, 0, true,  true,  STAGE_H(Ab, m0 + 128, k + 1, lds[1][1]), VMW(6));
    GPHASE(0, 1, 0, false, true,  STAGE_H(Bb, n0 + 128, k + 1, lds[1][3]), VMW(10));
    GPHASE(1, 0, 0, true,  false, STAGE_H(Ab, m0,       k + 2, lds[0][0]), (void)0);
    GPHASE(1, 1, 0, false, false, STAGE_H(Bb, n0,       k + 2, lds[0][2]), VMW(8));
    GPHASE(0, 0, 1, true,  true,  STAGE_H(Ab, m0 + 128, k + 2, lds[0][1]), VMW(6));
    GPHASE(0, 1, 1, false, true,  STAGE_H(Bb, n0 + 128, k + 2, lds[0][3]), VMW(10));
    GPHASE(1, 0, 1, true,  false, STAGE_H(Ab, m0,       k + 3, lds[1][0]), (void)0);
    GPHASE(1, 1, 1, false, false, STAGE_H(Bb, n0,       k + 3, lds[1][2]), VMW(8));
  }
  // peeled final iteration (k = KT-2): stage only A1/B1 of KT-1, drain once
  GPHASE(0, 0, 0, true,  true,  STAGE_H(Ab, m0 + 128, KT - 1, lds[1][1]), VMW(6));
  GPHASE(0, 1, 0, false, true,  STAGE_H(Bb, n0 + 128, KT - 1, lds[1][3]), VMW(10));
  GPHASE(1, 0, 0, true,  false, (void)0, (void)0);
  GPHASE(1, 1, 0, false, false, (void)0, VMW(0));
  GPHASE(0, 0, 1, true,  true,  (void)0, (void)0);
  GPHASE(0, 1, 1, false, true,  (void)0, (void)0);
  GPHASE(1, 0, 1, true,  false, (void)0, (void)0);
  GPHASE(1, 1, 1, false, false, (void)0, (void)0);

#undef GPHASE
#undef STAGE_H

#pragma unroll
  for (int mh = 0; mh < 2; ++mh)
#pragma unroll
    for (int nh = 0; nh < 2; ++nh)
#pragma unroll
      for (int mf = 0; mf < 4; ++mf)
#pragma unroll
        for (int nf = 0; nf < 2; ++nf)
#pragma unroll
          for (int t = 0; t < 4; ++t) {
            int row = m0 + mh * 128 + wr * 64 + mf * 16 + kg * 4 + t;
            int col = n0 + nh * 128 + wc * 32 + nf * 16 + r15;
            if (out_f32)
              ((float*)Cout)[(size_t)row * N + col] = acc[mh][nh][mf][nf][t];
            else
              ((unsigned short*)Cout)[(size_t)row * N + col] =
                  f2bf(acc[mh][nh][mf][nf][t]);
          }
}

// ---------------- flash attention (causal, GQA) ----------------
// 512 threads = 8 waves x 16 q-rows => 128 q-rows/block sharing one staged
// K/V tile (KVBLK=64). Double-buffered prefetch, one barrier per k-tile.
// Longest blocks dispatched first. Q pre-scaled by (1/sqrt(D))*log2(e).
// Q/K live in the fused QKV buffer: row stride QKVE elements.

__device__ __forceinline__ void sm_update(f32x4 sc[4], f32x4 o[8],
                                          float mrow[4], float lrow[4],
                                          bool diag, int qrow0, int kt,
                                          int r15, int kg, char* Pw) {
  if (diag) {
#pragma unroll
    for (int kf = 0; kf < 4; ++kf) {
      int kvg = kt * 64 + kf * 16 + r15;
#pragma unroll
      for (int t = 0; t < 4; ++t)
        if (kvg > qrow0 + kg * 4 + t) sc[kf][t] = -1e30f;
    }
  }
  float mx[4], sm[4];
#pragma unroll
  for (int t = 0; t < 4; ++t) {
    float v = fmaxf(fmaxf(sc[0][t], sc[1][t]), fmaxf(sc[2][t], sc[3][t]));
#pragma unroll
    for (int off = 1; off < 16; off <<= 1) v = fmaxf(v, __shfl_xor(v, off, 16));
    mx[t] = fmaxf(mrow[t], v);
    sm[t] = EXP2F(mrow[t] - mx[t]);
    mrow[t] = mx[t];
  }
#pragma unroll
  for (int kf = 0; kf < 4; ++kf)
#pragma unroll
    for (int t = 0; t < 4; ++t) sc[kf][t] = EXP2F(sc[kf][t] - mx[t]);
#pragma unroll
  for (int t = 0; t < 4; ++t) {
    float v = sc[0][t] + sc[1][t] + sc[2][t] + sc[3][t];
#pragma unroll
    for (int off = 1; off < 16; off <<= 1) v += __shfl_xor(v, off, 16);
    lrow[t] = lrow[t] * sm[t] + v;
  }
#pragma unroll
  for (int nf = 0; nf < 8; ++nf)
#pragma unroll
    for (int t = 0; t < 4; ++t) o[nf][t] *= sm[t];
  // P (C-layout) -> per-wave LDS (A-layout source), swizzled
#pragma unroll
  for (int kf = 0; kf < 4; ++kf)
#pragma unroll
    for (int t = 0; t < 4; ++t) {
      int r = kg * 4 + t, c = kf * 16 + r15;
      *(unsigned short*)(Pw + r * 128 + ((c * 2) ^ ((r & 7) << 4))) = f2bf(sc[kf][t]);
    }
}

__global__ __launch_bounds__(512, 4) void attn_kernel(
    const unsigned short* __restrict__ Q, const unsigned short* __restrict__ Kl,
    const unsigned short* __restrict__ Vt, unsigned short* __restrict__ AO) {
  __shared__ unsigned short Ks[2][64 * 128];   // [buf][kv][d], rows XOR-swizzled
  __shared__ unsigned short Vs[2][128 * 64];   // [buf][d][kv], rows XOR-swizzled
  __shared__ unsigned short Ps[8][16 * 64];    // per-wave P, swizzled
  const int tid = threadIdx.x, lane = tid & 63, wave = tid >> 6;
  const int h = blockIdx.x, b = blockIdx.z;
  const int qt = (QT - 1) - blockIdx.y;        // longest-first dispatch
  const int kvh = h >> 2;                      // G = 4
  const int r15 = lane & 15, kg = lane >> 4;
  const int qrow0 = qt * 128 + wave * 16;
  const int kmax = 2 * qt + 2;

  bf16x8 qf[4];
#pragma unroll
  for (int db = 0; db < 4; ++db)
    qf[db] = *(const bf16x8*)&Q[(size_t)(b * Sn + qrow0 + r15) * QKVE +
                                h * Dh + db * 32 + kg * 8];

  f32x4 o[8] = {};
  float mrow[4] = {-1e30f, -1e30f, -1e30f, -1e30f};
  float lrow[4] = {0.f, 0.f, 0.f, 0.f};

  const char* Kbase = (const char*)Kl + (size_t)(b * Sn) * (QKVE * 2) + kvh * 256;
  const char* Vbase = (const char*)Vt + (size_t)((b * NKV + kvh) * Dh) * (Sn * 2);

  auto stage = [&](int kt, int bi) {
#pragma unroll
    for (int c = 0; c < 2; ++c) {
      int f = (c * 512 + tid) * 16;
      int row = f >> 8, cb = f & 255;
      gl_lds16(Kbase + (size_t)(kt * 64 + row) * (QKVE * 2) + (cb ^ ((row & 7) << 4)),
               (char*)Ks[bi] + f);
    }
#pragma unroll
    for (int c = 0; c < 2; ++c) {
      int f = (c * 512 + tid) * 16;
      int row = f >> 7, cb = f & 127;
      gl_lds16(Vbase + (size_t)row * (Sn * 2) + kt * 128 + (cb ^ ((row & 7) << 4)),
               (char*)Vs[bi] + f);
    }
  };

  stage(0, 0);
  __syncthreads();

  for (int kt = 0; kt < kmax; ++kt) {
    const int cur = kt & 1;
    if (kt + 1 < kmax) stage(kt + 1, cur ^ 1);   // prefetch overlaps compute
    // skip tiles fully above the diagonal for this wave's strip (wave-uniform)
    if (kt * 64 <= qrow0 + 15) {
      const char* Kc = (const char*)Ks[cur];
      const char* Vc = (const char*)Vs[cur];
      f32x4 sc[4] = {};
      __builtin_amdgcn_s_setprio(1);
#pragma unroll
      for (int db = 0; db < 4; ++db) {
#pragma unroll
        for (int kf = 0; kf < 4; ++kf) {
          int krow = kf * 16 + r15;
          int cb = (db * 32 + kg * 8) * 2;
          bf16x8 kb = *(const bf16x8*)(Kc + krow * 256 + (cb ^ ((krow & 7) << 4)));
          sc[kf] = __builtin_amdgcn_mfma_f32_16x16x32_bf16(qf[db], kb, sc[kf], 0, 0, 0);
        }
      }
      __builtin_amdgcn_s_setprio(0);

      char* Pw = (char*)Ps[wave];
      bool diag = (kt * 64 + 63) > qrow0;        // tile touches the diagonal
      sm_update(sc, o, mrow, lrow, diag, qrow0, kt, r15, kg, Pw);

      __builtin_amdgcn_s_setprio(1);
#pragma unroll
      for (int ks = 0; ks < 2; ++ks) {
        bf16x8 pa = *(const bf16x8*)(Pw + r15 * 128 + ((kg * 16 + ks * 64) ^ ((r15 & 7) << 4)));
#pragma unroll
        for (int nf = 0; nf < 8; ++nf) {
          int vrow = nf * 16 + r15;
          int cb = (ks * 32 + kg * 8) * 2;
          bf16x8 vb = *(const bf16x8*)(Vc + vrow * 128 + (cb ^ ((vrow & 7) << 4)));
          o[nf] = __builtin_amdgcn_mfma_f32_16x16x32_bf16(pa, vb, o[nf], 0, 0, 0);
        }
      }
      __builtin_amdgcn_s_setprio(0);
    }
    __syncthreads();
  }

  float rinv[4];
#pragma unroll
  for (int t = 0; t < 4; ++t) rinv[t] = 1.0f / lrow[t];
#pragma unroll
  for (int nf = 0; nf < 8; ++nf)
#pragma unroll
    for (int t = 0; t < 4; ++t) {
      int srow = qrow0 + kg * 4 + t;
      AO[(size_t)(b * Sn + srow) * En + h * Dh + nf * 16 + r15] = f2bf(o[nf][t] * rinv[t]);
    }
}

// ---------------- launch ----------------

extern "C" void kernel_launch(void* const* d_in, const int* in_sizes, int n_in,
                              void* d_out, int out_size, void* d_ws, size_t ws_size,
                              hipStream_t stream) {
  const float* x  = (const float*)d_in[0];
  const float* Wq = (const float*)d_in[1];
  const float* Wk = (const float*)d_in[2];
  const float* Wv = (const float*)d_in[3];
  const float* Wo = (const float*)d_in[4];

  char* ws = (char*)d_ws;
  size_t off = 0;
  auto alloc = [&](size_t bytes) -> char* {
    char* p = ws + off;
    off += (bytes + 255) & ~(size_t)255;
    return p;
  };
  unsigned short* xb   = (unsigned short*)alloc((size_t)MT * En * 2);
  unsigned short* Wqkv = (unsigned short*)alloc((size_t)QKVE * En * 2); // rows: WqT|WkT|WvT
  unsigned short* WoT  = (unsigned short*)alloc((size_t)En * En * 2);
  unsigned short* Cqkv = (unsigned short*)alloc((size_t)MT * QKVE * 2); // [tok][Q|K|V]
  unsigned short* Vt   = (unsigned short*)alloc((size_t)MT * KVEn * 2);
  float2* cs           = (float2*)alloc((size_t)Sn * 64 * sizeof(float2));
  unsigned short* AO   = xb;   // alias: xb dead after the QKV projection

  cast_bf16_kernel<<<MT * (En / 4) / 256, 256, 0, stream>>>(x, xb, MT * En / 4);
  tcast_kernel<<<dim3(En / 32, En / 32), dim3(32, 32), 0, stream>>>(Wq, Wqkv, En, En);
  tcast_kernel<<<dim3(KVEn / 32, En / 32), dim3(32, 32), 0, stream>>>(
      Wk, Wqkv + (size_t)En * En, En, KVEn);
  tcast_kernel<<<dim3(KVEn / 32, En / 32), dim3(32, 32), 0, stream>>>(
      Wv, Wqkv + (size_t)(En + KVEn) * En, En, KVEn);
  tcast_kernel<<<dim3(En / 32, En / 32), dim3(32, 32), 0, stream>>>(Wo, WoT, En, En);
  rope_table_kernel<<<Sn * 64 / 256, 256, 0, stream>>>(cs);

  // fused QKV projection: [MT,4096] x [6144,4096]^T -> [MT,6144]
  gemm256_kernel<<<dim3(QKVE / 256, MT / 256), 512, 0, stream>>>(
      xb, Wqkv, Cqkv, MT, QKVE, En, 0);

  const float scl = 0.08838834764831845f * 1.4426950408889634f; // (1/sqrt(128))*log2(e)
  rope_kernel<<<dim3(MT, NH / 4), 256, 0, stream>>>(Cqkv, cs, QKVE, scl);
  rope_kernel<<<dim3(MT, NKV / 4), 256, 0, stream>>>(Cqkv + En, cs, QKVE, 1.0f);
  vtrans_kernel<<<dim3(Dh / 32, Sn / 32, Bn * NKV), dim3(32, 32), 0, stream>>>(
      Cqkv + En + KVEn, QKVE, Vt);

  attn_kernel<<<dim3(NH, QT, Bn), 512, 0, stream>>>(Cqkv, Cqkv + En, Vt, AO);

  gemm256_kernel<<<dim3(En / 256, MT / 256), 512, 0, stream>>>(
      AO, WoT, d_out, MT, En, En, 1);
}

// Round 11
// 572.862 us; speedup vs baseline: 2.7788x; 1.0750x over previous
//
#include <hip/hip_runtime.h>
#include <stdint.h>
#include <math.h>

typedef short bf16x8 __attribute__((ext_vector_type(8)));
typedef float f32x4 __attribute__((ext_vector_type(4)));

#if __has_builtin(__builtin_amdgcn_exp2f)
#define EXP2F(x) __builtin_amdgcn_exp2f(x)
#else
#define EXP2F(x) exp2f(x)
#endif

static constexpr int Bn   = 2;
static constexpr int Sn   = 2048;
static constexpr int NH   = 32;
static constexpr int NKV  = 8;
static constexpr int Dh   = 128;
static constexpr int En   = NH * Dh;     // 4096
static constexpr int KVEn = NKV * Dh;    // 1024
static constexpr int QKVE = En + 2 * KVEn; // 6144 fused projection width
static constexpr int MT   = Bn * Sn;     // 4096 tokens
static constexpr int QT   = Sn / 128;    // 16 q-tiles (128 rows each)

__device__ __forceinline__ unsigned short f2bf(float f) {
  unsigned int u = __float_as_uint(f);
  u += 0x7FFFu + ((u >> 16) & 1u);
  return (unsigned short)(u >> 16);
}
__device__ __forceinline__ float bf2f(unsigned short h) {
  return __uint_as_float(((unsigned int)h) << 16);
}

typedef __attribute__((address_space(1))) void* gas_t;
typedef __attribute__((address_space(3))) void* las_t;
// async global->LDS, 16B per lane; lds dest must be wave-base + lane*16 (linear)
__device__ __forceinline__ void gl_lds16(const void* g, void* l) {
  __builtin_amdgcn_global_load_lds((gas_t)(uintptr_t)g, (las_t)(uint32_t)(uintptr_t)l,
                                   16, 0, 0);
}

#define VMW(n)  asm volatile("s_waitcnt vmcnt(" #n ")" ::: "memory")
#define LGKM0   asm volatile("s_waitcnt lgkmcnt(0)" ::: "memory")
#define SCHEDB  __builtin_amdgcn_sched_barrier(0)
#define BAR     __builtin_amdgcn_s_barrier()

// ---------------- pre/post passes ----------------

__global__ void cast_bf16_kernel(const float* __restrict__ x,
                                 unsigned short* __restrict__ y, int n4) {
  int i = blockIdx.x * 256 + threadIdx.x;
  if (i >= n4) return;
  float4 v = ((const float4*)x)[i];
  ushort4 o;
  o.x = f2bf(v.x); o.y = f2bf(v.y); o.z = f2bf(v.z); o.w = f2bf(v.w);
  ((ushort4*)y)[i] = o;
}

// W [R][C] f32 -> WT [C][R] bf16. 64x64 tile, 256 thr; float4 reads,
// ushort4 writes (G13), padded LDS transpose (69-pad -> <=2-way, free).
__global__ void tcast_kernel(const float* __restrict__ W,
                             unsigned short* __restrict__ WT, int R, int C) {
  __shared__ float t[64][69];
  int tx = threadIdx.x & 15, ty = threadIdx.x >> 4;   // 16x16
  int r0 = blockIdx.y * 64, c0 = blockIdx.x * 64;
#pragma unroll
  for (int i = 0; i < 4; ++i) {
    float4 v = *(const float4*)&W[(size_t)(r0 + ty * 4 + i) * C + (c0 + tx * 4)];
    t[ty * 4 + i][tx * 4 + 0] = v.x;
    t[ty * 4 + i][tx * 4 + 1] = v.y;
    t[ty * 4 + i][tx * 4 + 2] = v.z;
    t[ty * 4 + i][tx * 4 + 3] = v.w;
  }
  __syncthreads();
#pragma unroll
  for (int i = 0; i < 4; ++i) {
    ushort4 o;
    o.x = f2bf(t[tx * 4 + 0][ty * 4 + i]);
    o.y = f2bf(t[tx * 4 + 1][ty * 4 + i]);
    o.z = f2bf(t[tx * 4 + 2][ty * 4 + i]);
    o.w = f2bf(t[tx * 4 + 3][ty * 4 + i]);
    *(ushort4*)&WT[(size_t)(c0 + ty * 4 + i) * R + (r0 + tx * 4)] = o;
  }
}

__global__ void rope_table_kernel(float2* __restrict__ cs) {
  int i = blockIdx.x * 256 + threadIdx.x;   // i < Sn*64
  int s = i >> 6, d = i & 63;
  float inv = powf(10000.0f, -(float)d * (1.0f / 64.0f));
  float a = (float)s * inv;
  cs[i] = make_float2(cosf(a), sinf(a));
}

// in-place RoPE, vectorized (G13): thread owns 8 pairs (d..d+7, d+64..d+71);
// short8 loads/stores. One block per token row; heads = blockDim.x/8.
__global__ void rope_kernel(unsigned short* __restrict__ q,
                            const float2* __restrict__ cs, int rowstride, float scl) {
  int row = blockIdx.x;
  int s = row & (Sn - 1);
  int h = threadIdx.x >> 3, d0 = (threadIdx.x & 7) * 8;
  size_t base = (size_t)row * rowstride + (size_t)h * Dh + d0;
  bf16x8 lo = *(const bf16x8*)&q[base];
  bf16x8 hi = *(const bf16x8*)&q[base + 64];
  bf16x8 olo, ohi;
#pragma unroll
  for (int e = 0; e < 8; ++e) {
    float2 c = cs[s * 64 + d0 + e];
    float x0 = bf2f((unsigned short)lo[e]);
    float x1 = bf2f((unsigned short)hi[e]);
    olo[e] = (short)f2bf((x0 * c.x - x1 * c.y) * scl);
    ohi[e] = (short)f2bf((x1 * c.x + x0 * c.y) * scl);
  }
  *(bf16x8*)&q[base] = olo;
  *(bf16x8*)&q[base + 64] = ohi;
}

// V (strided rows) -> Vt [B][KV][D][S]  (d-major so PV B-frags are k-contiguous)
__global__ void vtrans_kernel(const unsigned short* __restrict__ V, int rowstride,
                              unsigned short* __restrict__ Vt) {
  __shared__ unsigned short t[32][33];
  int bk = blockIdx.z;                 // b*NKV+kv
  int b = bk >> 3, kv = bk & 7;
  int d = blockIdx.x * 32 + threadIdx.x;
  int s = blockIdx.y * 32 + threadIdx.y;
  t[threadIdx.y][threadIdx.x] = V[(size_t)(b * Sn + s) * rowstride + kv * Dh + d];
  __syncthreads();
  int dd = blockIdx.x * 32 + threadIdx.y;
  int so = blockIdx.y * 32 + threadIdx.x;
  Vt[((size_t)bk * Dh + dd) * Sn + so] = t[threadIdx.x][threadIdx.y];
}

// ---------------- GEMM 256x256, true 8-phase (R4-exact, session best) --------
// A[M,K] bf16, BT[N,K] bf16 -> C[M,N]. 512 thr = 8 waves. BK=64.
// Phase = block-level C-quadrant 128x128 (all 8 waves remapped into it, 2x4,
// 64x32 piece each, 16 MFMA). 8 phases process 2 K-tiles; each phase stages
// exactly one half-tile (128x64, 2 gl_lds/thread). buf0 = even K-tiles,
// buf1 = odd. Counted vmcnt {6,10,-,8} from slot/landing proof; never drained
// to 0 in the main loop. Rows XOR-swizzled (row&7)<<4 on both sides.
// NOTE (R5-R8): T1 XCD remap, 4-bank frag pipeline, tail-read read-ahead all
// regressed vs this configuration — do not reapply without new evidence.

__global__ __launch_bounds__(512, 2) void gemm256_kernel(
    const unsigned short* __restrict__ A, const unsigned short* __restrict__ BT,
    void* __restrict__ Cout, int M, int N, int K, int out_f32) {
  __shared__ unsigned short lds[2][4][128 * 64];  // [buf][A0,A1,B0,B1]
  const int tid = threadIdx.x;
  const int lane = tid & 63, wave = tid >> 6;
  const int r15 = lane & 15, kg = lane >> 4;
  const int wr = wave >> 2, wc = wave & 3;        // wave pos within quadrant
  const int m0 = blockIdx.y * 256, n0 = blockIdx.x * 256;
  const char* Ab = (const char*)A;
  const char* Bb = (const char*)BT;
  const int KT = K >> 6;

  f32x4 acc[2][2][4][2] = {};   // [mh][nh][mf][nf]
  bf16x8 ar[4][2];              // current quadrant's A frags [mf][ks]
  bf16x8 br[2][2][2];           // persistent B frags [nh][nf][ks]

#define STAGE_H(SRC, ROW0, KT_, SLOT)                                         \
  do {                                                                        \
    _Pragma("unroll") for (int ld = 0; ld < 2; ++ld) {                        \
      int _f = (ld * 512 + tid) * 16;                                         \
      int _row = _f >> 7, _cb = _f & 127;                                     \
      gl_lds16(SRC + ((size_t)((ROW0) + _row) * K + (size_t)(KT_) * 64) * 2 + \
                   (_cb ^ ((_row & 7) << 4)),                                 \
               (char*)(SLOT) + _f);                                           \
    }                                                                         \
  } while (0)

#define GPHASE(MH, NH, BUF, DO_LDA, DO_LDB, STAGE_STMT, WAIT_STMT)            \
  do {                                                                        \
    if (DO_LDA) {                                                             \
      const char* _as = (const char*)lds[BUF][MH];                            \
      _Pragma("unroll") for (int mf = 0; mf < 4; ++mf) {                      \
        int _r = wr * 64 + mf * 16 + r15;                                     \
        int _sw = (_r & 7) << 4;                                              \
        ar[mf][0] = *(const bf16x8*)(_as + _r * 128 + ((kg * 16) ^ _sw));     \
        ar[mf][1] = *(const bf16x8*)(_as + _r * 128 + ((64 + kg * 16) ^ _sw));\
      }                                                                       \
    }                                                                         \
    if (DO_LDB) {                                                             \
      const char* _bs = (const char*)lds[BUF][2 + NH];                        \
      _Pragma("unroll") for (int nf = 0; nf < 2; ++nf) {                      \
        int _r = wc * 32 + nf * 16 + r15;                                     \
        int _sw = (_r & 7) << 4;                                              \
        br[NH][nf][0] =                                                       \
            *(const bf16x8*)(_bs + _r * 128 + ((kg * 16) ^ _sw));             \
        br[NH][nf][1] =                                                       \
            *(const bf16x8*)(_bs + _r * 128 + ((64 + kg * 16) ^ _sw));        \
      }                                                                       \
    }                                                                         \
    STAGE_STMT;                                                               \
    BAR;                                                                      \
    if ((DO_LDA) || (DO_LDB)) { LGKM0; }                                      \
    SCHEDB;                                                                   \
    __builtin_amdgcn_s_setprio(1);                                            \
    _Pragma("unroll") for (int mf = 0; mf < 4; ++mf)                          \
      _Pragma("unroll") for (int n2 = 0; n2 < 2; ++n2) {                      \
        acc[MH][NH][mf][n2] = __builtin_amdgcn_mfma_f32_16x16x32_bf16(        \
            ar[mf][0], br[NH][n2][0], acc[MH][NH][mf][n2], 0, 0, 0);          \
        acc[MH][NH][mf][n2] = __builtin_amdgcn_mfma_f32_16x16x32_bf16(        \
            ar[mf][1], br[NH][n2][1], acc[MH][NH][mf][n2], 0, 0, 0);          \
      }                                                                       \
    __builtin_amdgcn_s_setprio(0);                                            \
    SCHEDB;                                                                   \
    WAIT_STMT;                                                                \
    BAR;                                                                      \
    SCHEDB;                                                                   \
  } while (0)

  // prologue: halves in steady-state order A0(0),B0(0),A1(0),B1(0),A0(1),B0(1)
  STAGE_H(Ab, m0,       0, lds[0][0]);
  STAGE_H(Bb, n0,       0, lds[0][2]);
  STAGE_H(Ab, m0 + 128, 0, lds[0][1]);
  STAGE_H(Bb, n0 + 128, 0, lds[0][3]);
  STAGE_H(Ab, m0,       1, lds[1][0]);
  STAGE_H(Bb, n0,       1, lds[1][2]);
  VMW(8);
  SCHEDB;
  BAR;
  SCHEDB;

  for (int k = 0; k + 2 < KT; k += 2) {
    GPHASE(0, 0, 0, true,  true,  STAGE_H(Ab, m0 + 128, k + 1, lds[1][1]), VMW(6));
    GPHASE(0, 1, 0, false, true,  STAGE_H(Bb, n0 + 128, k + 1, lds[1][3]), VMW(10));
    GPHASE(1, 0, 0, true,  false, STAGE_H(Ab, m0,       k + 2, lds[0][0]), (void)0);
    GPHASE(1, 1, 0, false, false, STAGE_H(Bb, n0,       k + 2, lds[0][2]), VMW(8));
    GPHASE(0, 0, 1, true,  true,  STAGE_H(Ab, m0 + 128, k + 2, lds[0][1]), VMW(6));
    GPHASE(0, 1, 1, false, true,  STAGE_H(Bb, n0 + 128, k + 2, lds[0][3]), VMW(10));
    GPHASE(1, 0, 1, true,  false, STAGE_H(Ab, m0,       k + 3, lds[1][0]), (void)0);
    GPHASE(1, 1, 1, false, false, STAGE_H(Bb, n0,       k + 3, lds[1][2]), VMW(8));
  }
  // peeled final iteration (k = KT-2): stage only A1/B1 of KT-1, drain once
  GPHASE(0, 0, 0, true,  true,  STAGE_H(Ab, m0 + 128, KT - 1, lds[1][1]), VMW(6));
  GPHASE(0, 1, 0, false, true,  STAGE_H(Bb, n0 + 128, KT - 1, lds[1][3]), VMW(10));
  GPHASE(1, 0, 0, true,  false, (void)0, (void)0);
  GPHASE(1, 1, 0, false, false, (void)0, VMW(0));
  GPHASE(0, 0, 1, true,  true,  (void)0, (void)0);
  GPHASE(0, 1, 1, false, true,  (void)0, (void)0);
  GPHASE(1, 0, 1, true,  false, (void)0, (void)0);
  GPHASE(1, 1, 1, false, false, (void)0, (void)0);

#undef GPHASE
#undef STAGE_H

#pragma unroll
  for (int mh = 0; mh < 2; ++mh)
#pragma unroll
    for (int nh = 0; nh < 2; ++nh)
#pragma unroll
      for (int mf = 0; mf < 4; ++mf)
#pragma unroll
        for (int nf = 0; nf < 2; ++nf)
#pragma unroll
          for (int t = 0; t < 4; ++t) {
            int row = m0 + mh * 128 + wr * 64 + mf * 16 + kg * 4 + t;
            int col = n0 + nh * 128 + wc * 32 + nf * 16 + r15;
            if (out_f32)
              ((float*)Cout)[(size_t)row * N + col] = acc[mh][nh][mf][nf][t];
            else
              ((unsigned short*)Cout)[(size_t)row * N + col] =
                  f2bf(acc[mh][nh][mf][nf][t]);
          }
}

// ---------------- flash attention (causal, GQA) ----------------
// 512 threads = 8 waves x 16 q-rows => 128 q-rows/block sharing one staged
// K/V tile (KVBLK=64). Double-buffered prefetch, one barrier per k-tile.
// Longest blocks dispatched first. Q pre-scaled by (1/sqrt(D))*log2(e).
// T13 defer-max: skip o/l rescale while rowmax <= m+8 (P bounded by 2^8).

__device__ __forceinline__ void sm_update(f32x4 sc[4], f32x4 o[8],
                                          float mrow[4], float lrow[4],
                                          bool diag, int qrow0, int kt,
                                          int r15, int kg, char* Pw) {
  if (diag) {
#pragma unroll
    for (int kf = 0; kf < 4; ++kf) {
      int kvg = kt * 64 + kf * 16 + r15;
#pragma unroll
      for (int t = 0; t < 4; ++t)
        if (kvg > qrow0 + kg * 4 + t) sc[kf][t] = -1e30f;
    }
  }
  float nm[4];
  bool grow = false;
#pragma unroll
  for (int t = 0; t < 4; ++t) {
    float v = fmaxf(fmaxf(sc[0][t], sc[1][t]), fmaxf(sc[2][t], sc[3][t]));
#pragma unroll
    for (int off = 1; off < 16; off <<= 1) v = fmaxf(v, __shfl_xor(v, off, 16));
    nm[t] = v;
    grow = grow || (v > mrow[t] + 8.0f);
  }
  if (__any(grow)) {   // wave-uniform rescale (rare after warmup)
#pragma unroll
    for (int t = 0; t < 4; ++t) {
      float mx = fmaxf(mrow[t], nm[t]);
      float sm = EXP2F(mrow[t] - mx);
      mrow[t] = mx;
      lrow[t] *= sm;
#pragma unroll
      for (int nf = 0; nf < 8; ++nf) o[nf][t] *= sm;
    }
  }
#pragma unroll
  for (int kf = 0; kf < 4; ++kf)
#pragma unroll
    for (int t = 0; t < 4; ++t) sc[kf][t] = EXP2F(sc[kf][t] - mrow[t]);
#pragma unroll
  for (int t = 0; t < 4; ++t) {
    float v = sc[0][t] + sc[1][t] + sc[2][t] + sc[3][t];
#pragma unroll
    for (int off = 1; off < 16; off <<= 1) v += __shfl_xor(v, off, 16);
    lrow[t] += v;
  }
  // P (C-layout) -> per-wave LDS (A-layout source), swizzled
#pragma unroll
  for (int kf = 0; kf < 4; ++kf)
#pragma unroll
    for (int t = 0; t < 4; ++t) {
      int r = kg * 4 + t, c = kf * 16 + r15;
      *(unsigned short*)(Pw + r * 128 + ((c * 2) ^ ((r & 7) << 4))) = f2bf(sc[kf][t]);
    }
}

__global__ __launch_bounds__(512, 4) void attn_kernel(
    const unsigned short* __restrict__ Q, const unsigned short* __restrict__ Kl,
    const unsigned short* __restrict__ Vt, unsigned short* __restrict__ AO) {
  __shared__ unsigned short Ks[2][64 * 128];   // [buf][kv][d], rows XOR-swizzled
  __shared__ unsigned short Vs[2][128 * 64];   // [buf][d][kv], rows XOR-swizzled
  __shared__ unsigned short Ps[8][16 * 64];    // per-wave P, swizzled
  const int tid = threadIdx.x, lane = tid & 63, wave = tid >> 6;
  const int h = blockIdx.x, b = blockIdx.z;
  const int qt = (QT - 1) - blockIdx.y;        // longest-first dispatch
  const int kvh = h >> 2;                      // G = 4
  const int r15 = lane & 15, kg = lane >> 4;
  const int qrow0 = qt * 128 + wave * 16;
  const int kmax = 2 * qt + 2;

  bf16x8 qf[4];
#pragma unroll
  for (int db = 0; db < 4; ++db)
    qf[db] = *(const bf16x8*)&Q[(size_t)(b * Sn + qrow0 + r15) * QKVE +
                                h * Dh + db * 32 + kg * 8];

  f32x4 o[8] = {};
  float mrow[4] = {-1e30f, -1e30f, -1e30f, -1e30f};
  float lrow[4] = {0.f, 0.f, 0.f, 0.f};

  const char* Kbase = (const char*)Kl + (size_t)(b * Sn) * (QKVE * 2) + kvh * 256;
  const char* Vbase = (const char*)Vt + (size_t)((b * NKV + kvh) * Dh) * (Sn * 2);

  auto stage = [&](int kt, int bi) {
#pragma unroll
    for (int c = 0; c < 2; ++c) {
      int f = (c * 512 + tid) * 16;
      int row = f >> 8, cb = f & 255;
      gl_lds16(Kbase + (size_t)(kt * 64 + row) * (QKVE * 2) + (cb ^ ((row & 7) << 4)),
               (char*)Ks[bi] + f);
    }
#pragma unroll
    for (int c = 0; c < 2; ++c) {
      int f = (c * 512 + tid) * 16;
      int row = f >> 7, cb = f & 127;
      gl_lds16(Vbase + (size_t)row * (Sn * 2) + kt * 128 + (cb ^ ((row & 7) << 4)),
               (char*)Vs[bi] + f);
    }
  };

  stage(0, 0);
  __syncthreads();

  for (int kt = 0; kt < kmax; ++kt) {
    const int cur = kt & 1;
    if (kt + 1 < kmax) stage(kt + 1, cur ^ 1);   // prefetch overlaps compute
    // skip tiles fully above the diagonal for this wave's strip (wave-uniform)
    if (kt * 64 <= qrow0 + 15) {
      const char* Kc = (const char*)Ks[cur];
      const char* Vc = (const char*)Vs[cur];
      f32x4 sc[4] = {};
      __builtin_amdgcn_s_setprio(1);
#pragma unroll
      for (int db = 0; db < 4; ++db) {
#pragma unroll
        for (int kf = 0; kf < 4; ++kf) {
          int krow = kf * 16 + r15;
          int cb = (db * 32 + kg * 8) * 2;
          bf16x8 kb = *(const bf16x8*)(Kc + krow * 256 + (cb ^ ((krow & 7) << 4)));
          sc[kf] = __builtin_amdgcn_mfma_f32_16x16x32_bf16(qf[db], kb, sc[kf], 0, 0, 0);
        }
      }
      __builtin_amdgcn_s_setprio(0);

      char* Pw = (char*)Ps[wave];
      bool diag = (kt * 64 + 63) > qrow0;        // tile touches the diagonal
      sm_update(sc, o, mrow, lrow, diag, qrow0, kt, r15, kg, Pw);

      __builtin_amdgcn_s_setprio(1);
#pragma unroll
      for (int ks = 0; ks < 2; ++ks) {
        bf16x8 pa = *(const bf16x8*)(Pw + r15 * 128 + ((kg * 16 + ks * 64) ^ ((r15 & 7) << 4)));
#pragma unroll
        for (int nf = 0; nf < 8; ++nf) {
          int vrow = nf * 16 + r15;
          int cb = (ks * 32 + kg * 8) * 2;
          bf16x8 vb = *(const bf16x8*)(Vc + vrow * 128 + (cb ^ ((vrow & 7) << 4)));
          o[nf] = __builtin_amdgcn_mfma_f32_16x16x32_bf16(pa, vb, o[nf], 0, 0, 0);
        }
      }
      __builtin_amdgcn_s_setprio(0);
    }
    __syncthreads();
  }

  float rinv[4];
#pragma unroll
  for (int t = 0; t < 4; ++t) rinv[t] = 1.0f / lrow[t];
#pragma unroll
  for (int nf = 0; nf < 8; ++nf)
#pragma unroll
    for (int t = 0; t < 4; ++t) {
      int srow = qrow0 + kg * 4 + t;
      AO[(size_t)(b * Sn + srow) * En + h * Dh + nf * 16 + r15] = f2bf(o[nf][t] * rinv[t]);
    }
}

// ---------------- launch ----------------

extern "C" void kernel_launch(void* const* d_in, const int* in_sizes, int n_in,
                              void* d_out, int out_size, void* d_ws, size_t ws_size,
                              hipStream_t stream) {
  const float* x  = (const float*)d_in[0];
  const float* Wq = (const float*)d_in[1];
  const float* Wk = (const float*)d_in[2];
  const float* Wv = (const float*)d_in[3];
  const float* Wo = (const float*)d_in[4];

  char* ws = (char*)d_ws;
  size_t off = 0;
  auto alloc = [&](size_t bytes) -> char* {
    char* p = ws + off;
    off += (bytes + 255) & ~(size_t)255;
    return p;
  };
  unsigned short* xb   = (unsigned short*)alloc((size_t)MT * En * 2);
  unsigned short* Wqkv = (unsigned short*)alloc((size_t)QKVE * En * 2); // rows: WqT|WkT|WvT
  unsigned short* WoT  = (unsigned short*)alloc((size_t)En * En * 2);
  unsigned short* Cqkv = (unsigned short*)alloc((size_t)MT * QKVE * 2); // [tok][Q|K|V]
  unsigned short* Vt   = (unsigned short*)alloc((size_t)MT * KVEn * 2);
  float2* cs           = (float2*)alloc((size_t)Sn * 64 * sizeof(float2));
  unsigned short* AO   = xb;   // alias: xb dead after the QKV projection

  cast_bf16_kernel<<<MT * (En / 4) / 256, 256, 0, stream>>>(x, xb, MT * En / 4);
  tcast_kernel<<<dim3(En / 64, En / 64), 256, 0, stream>>>(Wq, Wqkv, En, En);
  tcast_kernel<<<dim3(KVEn / 64, En / 64), 256, 0, stream>>>(
      Wk, Wqkv + (size_t)En * En, En, KVEn);
  tcast_kernel<<<dim3(KVEn / 64, En / 64), 256, 0, stream>>>(
      Wv, Wqkv + (size_t)(En + KVEn) * En, En, KVEn);
  tcast_kernel<<<dim3(En / 64, En / 64), 256, 0, stream>>>(Wo, WoT, En, En);
  rope_table_kernel<<<Sn * 64 / 256, 256, 0, stream>>>(cs);

  // fused QKV projection: [MT,4096] x [6144,4096]^T -> [MT,6144]
  gemm256_kernel<<<dim3(QKVE / 256, MT / 256), 512, 0, stream>>>(
      xb, Wqkv, Cqkv, MT, QKVE, En, 0);

  const float scl = 0.08838834764831845f * 1.4426950408889634f; // (1/sqrt(128))*log2(e)
  rope_kernel<<<MT, 256, 0, stream>>>(Cqkv, cs, QKVE, scl);        // Q: 32 heads
  rope_kernel<<<MT, 64, 0, stream>>>(Cqkv + En, cs, QKVE, 1.0f);   // K: 8 heads
  vtrans_kernel<<<dim3(Dh / 32, Sn / 32, Bn * NKV), dim3(32, 32), 0, stream>>>(
      Cqkv + En + KVEn, QKVE, Vt);

  attn_kernel<<<dim3(NH, QT, Bn), 512, 0, stream>>>(Cqkv, Cqkv + En, Vt, AO);

  gemm256_kernel<<<dim3(En / 256, MT / 256), 512, 0, stream>>>(
      AO, WoT, d_out, MT, En, En, 1);
}

// Round 12
// 554.703 us; speedup vs baseline: 2.8697x; 1.0327x over previous
//
#include <hip/hip_runtime.h>
#include <stdint.h>
#include <math.h>

typedef short bf16x8 __attribute__((ext_vector_type(8)));
typedef float f32x4 __attribute__((ext_vector_type(4)));

#if __has_builtin(__builtin_amdgcn_exp2f)
#define EXP2F(x) __builtin_amdgcn_exp2f(x)
#else
#define EXP2F(x) exp2f(x)
#endif

static constexpr int Bn   = 2;
static constexpr int Sn   = 2048;
static constexpr int NH   = 32;
static constexpr int NKV  = 8;
static constexpr int Dh   = 128;
static constexpr int En   = NH * Dh;     // 4096
static constexpr int KVEn = NKV * Dh;    // 1024
static constexpr int QKVE = En + 2 * KVEn; // 6144 fused projection width
static constexpr int MT   = Bn * Sn;     // 4096 tokens
static constexpr int QT   = Sn / 128;    // 16 q-tiles (128 rows each)

__device__ __forceinline__ unsigned short f2bf(float f) {
  unsigned int u = __float_as_uint(f);
  u += 0x7FFFu + ((u >> 16) & 1u);
  return (unsigned short)(u >> 16);
}
__device__ __forceinline__ float bf2f(unsigned short h) {
  return __uint_as_float(((unsigned int)h) << 16);
}

typedef __attribute__((address_space(1))) void* gas_t;
typedef __attribute__((address_space(3))) void* las_t;
// async global->LDS, 16B per lane; lds dest must be wave-base + lane*16 (linear)
__device__ __forceinline__ void gl_lds16(const void* g, void* l) {
  __builtin_amdgcn_global_load_lds((gas_t)(uintptr_t)g, (las_t)(uint32_t)(uintptr_t)l,
                                   16, 0, 0);
}

#define VMW(n)  asm volatile("s_waitcnt vmcnt(" #n ")" ::: "memory")
#define LGKM0   asm volatile("s_waitcnt lgkmcnt(0)" ::: "memory")
#define SCHEDB  __builtin_amdgcn_sched_barrier(0)
#define BAR     __builtin_amdgcn_s_barrier()

// ---------------- pre/post passes ----------------

__global__ void cast_bf16_kernel(const float* __restrict__ x,
                                 unsigned short* __restrict__ y, int n4) {
  int i = blockIdx.x * 256 + threadIdx.x;
  if (i >= n4) return;
  float4 v = ((const float4*)x)[i];
  ushort4 o;
  o.x = f2bf(v.x); o.y = f2bf(v.y); o.z = f2bf(v.z); o.w = f2bf(v.w);
  ((ushort4*)y)[i] = o;
}

// W [R][C] f32 -> WT [C][R] bf16. 64x64 tile, 256 thr; float4 reads,
// ushort4 writes (G13), padded LDS transpose (69-pad -> <=2-way, free).
__global__ void tcast_kernel(const float* __restrict__ W,
                             unsigned short* __restrict__ WT, int R, int C) {
  __shared__ float t[64][69];
  int tx = threadIdx.x & 15, ty = threadIdx.x >> 4;   // 16x16
  int r0 = blockIdx.y * 64, c0 = blockIdx.x * 64;
#pragma unroll
  for (int i = 0; i < 4; ++i) {
    float4 v = *(const float4*)&W[(size_t)(r0 + ty * 4 + i) * C + (c0 + tx * 4)];
    t[ty * 4 + i][tx * 4 + 0] = v.x;
    t[ty * 4 + i][tx * 4 + 1] = v.y;
    t[ty * 4 + i][tx * 4 + 2] = v.z;
    t[ty * 4 + i][tx * 4 + 3] = v.w;
  }
  __syncthreads();
#pragma unroll
  for (int i = 0; i < 4; ++i) {
    ushort4 o;
    o.x = f2bf(t[tx * 4 + 0][ty * 4 + i]);
    o.y = f2bf(t[tx * 4 + 1][ty * 4 + i]);
    o.z = f2bf(t[tx * 4 + 2][ty * 4 + i]);
    o.w = f2bf(t[tx * 4 + 3][ty * 4 + i]);
    *(ushort4*)&WT[(size_t)(c0 + ty * 4 + i) * R + (r0 + tx * 4)] = o;
  }
}

__global__ void rope_table_kernel(float2* __restrict__ cs) {
  int i = blockIdx.x * 256 + threadIdx.x;   // i < Sn*64
  int s = i >> 6, d = i & 63;
  float inv = powf(10000.0f, -(float)d * (1.0f / 64.0f));
  float a = (float)s * inv;
  cs[i] = make_float2(cosf(a), sinf(a));
}

// in-place RoPE, vectorized (G13): thread owns 8 pairs (d..d+7, d+64..d+71);
// short8 loads/stores. One block per token row; heads = blockDim.x/8.
__global__ void rope_kernel(unsigned short* __restrict__ q,
                            const float2* __restrict__ cs, int rowstride, float scl) {
  int row = blockIdx.x;
  int s = row & (Sn - 1);
  int h = threadIdx.x >> 3, d0 = (threadIdx.x & 7) * 8;
  size_t base = (size_t)row * rowstride + (size_t)h * Dh + d0;
  bf16x8 lo = *(const bf16x8*)&q[base];
  bf16x8 hi = *(const bf16x8*)&q[base + 64];
  bf16x8 olo, ohi;
#pragma unroll
  for (int e = 0; e < 8; ++e) {
    float2 c = cs[s * 64 + d0 + e];
    float x0 = bf2f((unsigned short)lo[e]);
    float x1 = bf2f((unsigned short)hi[e]);
    olo[e] = (short)f2bf((x0 * c.x - x1 * c.y) * scl);
    ohi[e] = (short)f2bf((x1 * c.x + x0 * c.y) * scl);
  }
  *(bf16x8*)&q[base] = olo;
  *(bf16x8*)&q[base + 64] = ohi;
}

// V (strided rows) -> Vt [B][KV][D][S]  (d-major so PV B-frags are k-contiguous)
__global__ void vtrans_kernel(const unsigned short* __restrict__ V, int rowstride,
                              unsigned short* __restrict__ Vt) {
  __shared__ unsigned short t[32][33];
  int bk = blockIdx.z;                 // b*NKV+kv
  int b = bk >> 3, kv = bk & 7;
  int d = blockIdx.x * 32 + threadIdx.x;
  int s = blockIdx.y * 32 + threadIdx.y;
  t[threadIdx.y][threadIdx.x] = V[(size_t)(b * Sn + s) * rowstride + kv * Dh + d];
  __syncthreads();
  int dd = blockIdx.x * 32 + threadIdx.y;
  int so = blockIdx.y * 32 + threadIdx.x;
  Vt[((size_t)bk * Dh + dd) * Sn + so] = t[threadIdx.x][threadIdx.y];
}

// ---------------- GEMM 256x256, 8-phase, single-barrier phases --------------
// R4 ladder (stage order, slots, vmcnt {6,10,-,8}) kept bit-identical; the
// leading per-phase barrier is removed (R11). Safety proof: (a) RD landing
// guaranteed by earlier-phase VMW + trailing BAR; (b) every re-staged slot's
// last reader LGKM0-drained >=1 trailing-BAR earlier (all 8 phases audited;
// same-phase RD/STAGE slots disjoint); (c) vmcnt is per-wave, barrier-free.
// Phase = {RD; STAGE; LGKM0; MFMA; VMW; BAR}. 16 -> 8 barriers per iter.
// NOTE (R5-R8): T1 XCD remap, 4-bank frag pipeline, tail-read read-ahead all
// regressed vs this configuration — do not reapply without new evidence.

__global__ __launch_bounds__(512, 2) void gemm256_kernel(
    const unsigned short* __restrict__ A, const unsigned short* __restrict__ BT,
    void* __restrict__ Cout, int M, int N, int K, int out_f32) {
  __shared__ unsigned short lds[2][4][128 * 64];  // [buf][A0,A1,B0,B1]
  const int tid = threadIdx.x;
  const int lane = tid & 63, wave = tid >> 6;
  const int r15 = lane & 15, kg = lane >> 4;
  const int wr = wave >> 2, wc = wave & 3;        // wave pos within quadrant
  const int m0 = blockIdx.y * 256, n0 = blockIdx.x * 256;
  const char* Ab = (const char*)A;
  const char* Bb = (const char*)BT;
  const int KT = K >> 6;

  f32x4 acc[2][2][4][2] = {};   // [mh][nh][mf][nf]
  bf16x8 ar[4][2];              // current quadrant's A frags [mf][ks]
  bf16x8 br[2][2][2];           // persistent B frags [nh][nf][ks]

#define STAGE_H(SRC, ROW0, KT_, SLOT)                                         \
  do {                                                                        \
    _Pragma("unroll") for (int ld = 0; ld < 2; ++ld) {                        \
      int _f = (ld * 512 + tid) * 16;                                         \
      int _row = _f >> 7, _cb = _f & 127;                                     \
      gl_lds16(SRC + ((size_t)((ROW0) + _row) * K + (size_t)(KT_) * 64) * 2 + \
                   (_cb ^ ((_row & 7) << 4)),                                 \
               (char*)(SLOT) + _f);                                           \
    }                                                                         \
  } while (0)

#define GPHASE(MH, NH, BUF, DO_LDA, DO_LDB, STAGE_STMT, WAIT_STMT)            \
  do {                                                                        \
    if (DO_LDA) {                                                             \
      const char* _as = (const char*)lds[BUF][MH];                            \
      _Pragma("unroll") for (int mf = 0; mf < 4; ++mf) {                      \
        int _r = wr * 64 + mf * 16 + r15;                                     \
        int _sw = (_r & 7) << 4;                                              \
        ar[mf][0] = *(const bf16x8*)(_as + _r * 128 + ((kg * 16) ^ _sw));     \
        ar[mf][1] = *(const bf16x8*)(_as + _r * 128 + ((64 + kg * 16) ^ _sw));\
      }                                                                       \
    }                                                                         \
    if (DO_LDB) {                                                             \
      const char* _bs = (const char*)lds[BUF][2 + NH];                        \
      _Pragma("unroll") for (int nf = 0; nf < 2; ++nf) {                      \
        int _r = wc * 32 + nf * 16 + r15;                                     \
        int _sw = (_r & 7) << 4;                                              \
        br[NH][nf][0] =                                                       \
            *(const bf16x8*)(_bs + _r * 128 + ((kg * 16) ^ _sw));             \
        br[NH][nf][1] =                                                       \
            *(const bf16x8*)(_bs + _r * 128 + ((64 + kg * 16) ^ _sw));        \
      }                                                                       \
    }                                                                         \
    STAGE_STMT;                                                               \
    if ((DO_LDA) || (DO_LDB)) { LGKM0; }                                      \
    SCHEDB;                                                                   \
    __builtin_amdgcn_s_setprio(1);                                            \
    _Pragma("unroll") for (int mf = 0; mf < 4; ++mf)                          \
      _Pragma("unroll") for (int n2 = 0; n2 < 2; ++n2) {                      \
        acc[MH][NH][mf][n2] = __builtin_amdgcn_mfma_f32_16x16x32_bf16(        \
            ar[mf][0], br[NH][n2][0], acc[MH][NH][mf][n2], 0, 0, 0);          \
        acc[MH][NH][mf][n2] = __builtin_amdgcn_mfma_f32_16x16x32_bf16(        \
            ar[mf][1], br[NH][n2][1], acc[MH][NH][mf][n2], 0, 0, 0);          \
      }                                                                       \
    __builtin_amdgcn_s_setprio(0);                                            \
    SCHEDB;                                                                   \
    WAIT_STMT;                                                                \
    BAR;                                                                      \
    SCHEDB;                                                                   \
  } while (0)

  // prologue: halves in steady-state order A0(0),B0(0),A1(0),B1(0),A0(1),B0(1)
  STAGE_H(Ab, m0,       0, lds[0][0]);
  STAGE_H(Bb, n0,       0, lds[0][2]);
  STAGE_H(Ab, m0 + 128, 0, lds[0][1]);
  STAGE_H(Bb, n0 + 128, 0, lds[0][3]);
  STAGE_H(Ab, m0,       1, lds[1][0]);
  STAGE_H(Bb, n0,       1, lds[1][2]);
  VMW(8);
  SCHEDB;
  BAR;
  SCHEDB;

  for (int k = 0; k + 2 < KT; k += 2) {
    GPHASE(0, 0, 0, true,  true,  STAGE_H(Ab, m0 + 128, k + 1, lds[1][1]), VMW(6));
    GPHASE(0, 1, 0, false, true,  STAGE_H(Bb, n0 + 128, k + 1, lds[1][3]), VMW(10));
    GPHASE(1, 0, 0, true,  false, STAGE_H(Ab, m0,       k + 2, lds[0][0]), (void)0);
    GPHASE(1, 1, 0, false, false, STAGE_H(Bb, n0,       k + 2, lds[0][2]), VMW(8));
    GPHASE(0, 0, 1, true,  true,  STAGE_H(Ab, m0 + 128, k + 2, lds[0][1]), VMW(6));
    GPHASE(0, 1, 1, false, true,  STAGE_H(Bb, n0 + 128, k + 2, lds[0][3]), VMW(10));
    GPHASE(1, 0, 1, true,  false, STAGE_H(Ab, m0,       k + 3, lds[1][0]), (void)0);
    GPHASE(1, 1, 1, false, false, STAGE_H(Bb, n0,       k + 3, lds[1][2]), VMW(8));
  }
  // peeled final iteration (k = KT-2): stage only A1/B1 of KT-1, drain once
  GPHASE(0, 0, 0, true,  true,  STAGE_H(Ab, m0 + 128, KT - 1, lds[1][1]), VMW(6));
  GPHASE(0, 1, 0, false, true,  STAGE_H(Bb, n0 + 128, KT - 1, lds[1][3]), VMW(10));
  GPHASE(1, 0, 0, true,  false, (void)0, (void)0);
  GPHASE(1, 1, 0, false, false, (void)0, VMW(0));
  GPHASE(0, 0, 1, true,  true,  (void)0, (void)0);
  GPHASE(0, 1, 1, false, true,  (void)0, (void)0);
  GPHASE(1, 0, 1, true,  false, (void)0, (void)0);
  GPHASE(1, 1, 1, false, false, (void)0, (void)0);

#undef GPHASE
#undef STAGE_H

#pragma unroll
  for (int mh = 0; mh < 2; ++mh)
#pragma unroll
    for (int nh = 0; nh < 2; ++nh)
#pragma unroll
      for (int mf = 0; mf < 4; ++mf)
#pragma unroll
        for (int nf = 0; nf < 2; ++nf)
#pragma unroll
          for (int t = 0; t < 4; ++t) {
            int row = m0 + mh * 128 + wr * 64 + mf * 16 + kg * 4 + t;
            int col = n0 + nh * 128 + wc * 32 + nf * 16 + r15;
            if (out_f32)
              ((float*)Cout)[(size_t)row * N + col] = acc[mh][nh][mf][nf][t];
            else
              ((unsigned short*)Cout)[(size_t)row * N + col] =
                  f2bf(acc[mh][nh][mf][nf][t]);
          }
}

// ---------------- flash attention (causal, GQA) ----------------
// 512 threads = 8 waves x 16 q-rows => 128 q-rows/block sharing one staged
// K/V tile (KVBLK=64). Double-buffered prefetch, one barrier per k-tile.
// Longest blocks dispatched first. Q pre-scaled by (1/sqrt(D))*log2(e).
// T13 defer-max: skip o/l rescale while rowmax <= m+8 (P bounded by 2^8).

__device__ __forceinline__ void sm_update(f32x4 sc[4], f32x4 o[8],
                                          float mrow[4], float lrow[4],
                                          bool diag, int qrow0, int kt,
                                          int r15, int kg, char* Pw) {
  if (diag) {
#pragma unroll
    for (int kf = 0; kf < 4; ++kf) {
      int kvg = kt * 64 + kf * 16 + r15;
#pragma unroll
      for (int t = 0; t < 4; ++t)
        if (kvg > qrow0 + kg * 4 + t) sc[kf][t] = -1e30f;
    }
  }
  float nm[4];
  bool grow = false;
#pragma unroll
  for (int t = 0; t < 4; ++t) {
    float v = fmaxf(fmaxf(sc[0][t], sc[1][t]), fmaxf(sc[2][t], sc[3][t]));
#pragma unroll
    for (int off = 1; off < 16; off <<= 1) v = fmaxf(v, __shfl_xor(v, off, 16));
    nm[t] = v;
    grow = grow || (v > mrow[t] + 8.0f);
  }
  if (__any(grow)) {   // wave-uniform rescale (rare after warmup)
#pragma unroll
    for (int t = 0; t < 4; ++t) {
      float mx = fmaxf(mrow[t], nm[t]);
      float sm = EXP2F(mrow[t] - mx);
      mrow[t] = mx;
      lrow[t] *= sm;
#pragma unroll
      for (int nf = 0; nf < 8; ++nf) o[nf][t] *= sm;
    }
  }
#pragma unroll
  for (int kf = 0; kf < 4; ++kf)
#pragma unroll
    for (int t = 0; t < 4; ++t) sc[kf][t] = EXP2F(sc[kf][t] - mrow[t]);
#pragma unroll
  for (int t = 0; t < 4; ++t) {
    float v = sc[0][t] + sc[1][t] + sc[2][t] + sc[3][t];
#pragma unroll
    for (int off = 1; off < 16; off <<= 1) v += __shfl_xor(v, off, 16);
    lrow[t] += v;
  }
  // P (C-layout) -> per-wave LDS (A-layout source), swizzled
#pragma unroll
  for (int kf = 0; kf < 4; ++kf)
#pragma unroll
    for (int t = 0; t < 4; ++t) {
      int r = kg * 4 + t, c = kf * 16 + r15;
      *(unsigned short*)(Pw + r * 128 + ((c * 2) ^ ((r & 7) << 4))) = f2bf(sc[kf][t]);
    }
}

__global__ __launch_bounds__(512, 4) void attn_kernel(
    const unsigned short* __restrict__ Q, const unsigned short* __restrict__ Kl,
    const unsigned short* __restrict__ Vt, unsigned short* __restrict__ AO) {
  __shared__ unsigned short Ks[2][64 * 128];   // [buf][kv][d], rows XOR-swizzled
  __shared__ unsigned short Vs[2][128 * 64];   // [buf][d][kv], rows XOR-swizzled
  __shared__ unsigned short Ps[8][16 * 64];    // per-wave P, swizzled
  const int tid = threadIdx.x, lane = tid & 63, wave = tid >> 6;
  const int h = blockIdx.x, b = blockIdx.z;
  const int qt = (QT - 1) - blockIdx.y;        // longest-first dispatch
  const int kvh = h >> 2;                      // G = 4
  const int r15 = lane & 15, kg = lane >> 4;
  const int qrow0 = qt * 128 + wave * 16;
  const int kmax = 2 * qt + 2;

  bf16x8 qf[4];
#pragma unroll
  for (int db = 0; db < 4; ++db)
    qf[db] = *(const bf16x8*)&Q[(size_t)(b * Sn + qrow0 + r15) * QKVE +
                                h * Dh + db * 32 + kg * 8];

  f32x4 o[8] = {};
  float mrow[4] = {-1e30f, -1e30f, -1e30f, -1e30f};
  float lrow[4] = {0.f, 0.f, 0.f, 0.f};

  const char* Kbase = (const char*)Kl + (size_t)(b * Sn) * (QKVE * 2) + kvh * 256;
  const char* Vbase = (const char*)Vt + (size_t)((b * NKV + kvh) * Dh) * (Sn * 2);

  auto stage = [&](int kt, int bi) {
#pragma unroll
    for (int c = 0; c < 2; ++c) {
      int f = (c * 512 + tid) * 16;
      int row = f >> 8, cb = f & 255;
      gl_lds16(Kbase + (size_t)(kt * 64 + row) * (QKVE * 2) + (cb ^ ((row & 7) << 4)),
               (char*)Ks[bi] + f);
    }
#pragma unroll
    for (int c = 0; c < 2; ++c) {
      int f = (c * 512 + tid) * 16;
      int row = f >> 7, cb = f & 127;
      gl_lds16(Vbase + (size_t)row * (Sn * 2) + kt * 128 + (cb ^ ((row & 7) << 4)),
               (char*)Vs[bi] + f);
    }
  };

  stage(0, 0);
  __syncthreads();

  for (int kt = 0; kt < kmax; ++kt) {
    const int cur = kt & 1;
    if (kt + 1 < kmax) stage(kt + 1, cur ^ 1);   // prefetch overlaps compute
    // skip tiles fully above the diagonal for this wave's strip (wave-uniform)
    if (kt * 64 <= qrow0 + 15) {
      const char* Kc = (const char*)Ks[cur];
      const char* Vc = (const char*)Vs[cur];
      f32x4 sc[4] = {};
      __builtin_amdgcn_s_setprio(1);
#pragma unroll
      for (int db = 0; db < 4; ++db) {
#pragma unroll
        for (int kf = 0; kf < 4; ++kf) {
          int krow = kf * 16 + r15;
          int cb = (db * 32 + kg * 8) * 2;
          bf16x8 kb = *(const bf16x8*)(Kc + krow * 256 + (cb ^ ((krow & 7) << 4)));
          sc[kf] = __builtin_amdgcn_mfma_f32_16x16x32_bf16(qf[db], kb, sc[kf], 0, 0, 0);
        }
      }
      __builtin_amdgcn_s_setprio(0);

      char* Pw = (char*)Ps[wave];
      bool diag = (kt * 64 + 63) > qrow0;        // tile touches the diagonal
      sm_update(sc, o, mrow, lrow, diag, qrow0, kt, r15, kg, Pw);

      __builtin_amdgcn_s_setprio(1);
#pragma unroll
      for (int ks = 0; ks < 2; ++ks) {
        bf16x8 pa = *(const bf16x8*)(Pw + r15 * 128 + ((kg * 16 + ks * 64) ^ ((r15 & 7) << 4)));
#pragma unroll
        for (int nf = 0; nf < 8; ++nf) {
          int vrow = nf * 16 + r15;
          int cb = (ks * 32 + kg * 8) * 2;
          bf16x8 vb = *(const bf16x8*)(Vc + vrow * 128 + (cb ^ ((vrow & 7) << 4)));
          o[nf] = __builtin_amdgcn_mfma_f32_16x16x32_bf16(pa, vb, o[nf], 0, 0, 0);
        }
      }
      __builtin_amdgcn_s_setprio(0);
    }
    __syncthreads();
  }

  float rinv[4];
#pragma unroll
  for (int t = 0; t < 4; ++t) rinv[t] = 1.0f / lrow[t];
#pragma unroll
  for (int nf = 0; nf < 8; ++nf)
#pragma unroll
    for (int t = 0; t < 4; ++t) {
      int srow = qrow0 + kg * 4 + t;
      AO[(size_t)(b * Sn + srow) * En + h * Dh + nf * 16 + r15] = f2bf(o[nf][t] * rinv[t]);
    }
}

// ---------------- launch ----------------

extern "C" void kernel_launch(void* const* d_in, const int* in_sizes, int n_in,
                              void* d_out, int out_size, void* d_ws, size_t ws_size,
                              hipStream_t stream) {
  const float* x  = (const float*)d_in[0];
  const float* Wq = (const float*)d_in[1];
  const float* Wk = (const float*)d_in[2];
  const float* Wv = (const float*)d_in[3];
  const float* Wo = (const float*)d_in[4];

  char* ws = (char*)d_ws;
  size_t off = 0;
  auto alloc = [&](size_t bytes) -> char* {
    char* p = ws + off;
    off += (bytes + 255) & ~(size_t)255;
    return p;
  };
  unsigned short* xb   = (unsigned short*)alloc((size_t)MT * En * 2);
  unsigned short* Wqkv = (unsigned short*)alloc((size_t)QKVE * En * 2); // rows: WqT|WkT|WvT
  unsigned short* WoT  = (unsigned short*)alloc((size_t)En * En * 2);
  unsigned short* Cqkv = (unsigned short*)alloc((size_t)MT * QKVE * 2); // [tok][Q|K|V]
  unsigned short* Vt   = (unsigned short*)alloc((size_t)MT * KVEn * 2);
  float2* cs           = (float2*)alloc((size_t)Sn * 64 * sizeof(float2));
  unsigned short* AO   = xb;   // alias: xb dead after the QKV projection

  cast_bf16_kernel<<<MT * (En / 4) / 256, 256, 0, stream>>>(x, xb, MT * En / 4);
  tcast_kernel<<<dim3(En / 64, En / 64), 256, 0, stream>>>(Wq, Wqkv, En, En);
  tcast_kernel<<<dim3(KVEn / 64, En / 64), 256, 0, stream>>>(
      Wk, Wqkv + (size_t)En * En, En, KVEn);
  tcast_kernel<<<dim3(KVEn / 64, En / 64), 256, 0, stream>>>(
      Wv, Wqkv + (size_t)(En + KVEn) * En, En, KVEn);
  tcast_kernel<<<dim3(En / 64, En / 64), 256, 0, stream>>>(Wo, WoT, En, En);
  rope_table_kernel<<<Sn * 64 / 256, 256, 0, stream>>>(cs);

  // fused QKV projection: [MT,4096] x [6144,4096]^T -> [MT,6144]
  gemm256_kernel<<<dim3(QKVE / 256, MT / 256), 512, 0, stream>>>(
      xb, Wqkv, Cqkv, MT, QKVE, En, 0);

  const float scl = 0.08838834764831845f * 1.4426950408889634f; // (1/sqrt(128))*log2(e)
  rope_kernel<<<MT, 256, 0, stream>>>(Cqkv, cs, QKVE, scl);        // Q: 32 heads
  rope_kernel<<<MT, 64, 0, stream>>>(Cqkv + En, cs, QKVE, 1.0f);   // K: 8 heads
  vtrans_kernel<<<dim3(Dh / 32, Sn / 32, Bn * NKV), dim3(32, 32), 0, stream>>>(
      Cqkv + En + KVEn, QKVE, Vt);

  attn_kernel<<<dim3(NH, QT, Bn), 512, 0, stream>>>(Cqkv, Cqkv + En, Vt, AO);

  gemm256_kernel<<<dim3(En / 256, MT / 256), 512, 0, stream>>>(
      AO, WoT, d_out, MT, En, En, 1);
}